// Round 9
// baseline (243.637 us; speedup 1.0000x reference)
//
#include <hip/hip_runtime.h>
#include <hip/hip_bf16.h>

// NonLocalBlock B=4,C=256,H=W=64 (N=4096) — round 13.
//  Mechanism: TLP. attn is latency/occupancy-bound (r12 null + 42% no-issue
//  cycles + occupancy 21%). Split-K: 512 blocks, each does its 64 q-rows x
//  HALF the K range (32 tiles) -> per-CU bytes & FLOPs unchanged, but LDS
//  dieted to EXACTLY 80KB (Ps pad -> 16B-granule XOR swizzle, lpart/linv
//  alias dead Ps space) so 2 blocks co-reside per CU and cover each other's
//  stalls. Each half writes locally-normalized O-hat + l to workspace; new
//  proj_kernel blends the two halves (w = l0/(l0+l1)) and runs the proven
//  proj+residual epilogue verbatim.
// ws = KT | V8 | W8 | Opart | Lw = 32.6 MiB.

typedef __attribute__((ext_vector_type(4))) short s16x4;
typedef __attribute__((ext_vector_type(8))) short s16x8;
typedef __attribute__((ext_vector_type(16))) float f32x16;

#define MFMA32(a, b, c) __builtin_amdgcn_mfma_f32_32x32x16_bf16((a), (b), (c), 0, 0, 0)

constexpr int Cc = 256;
constexpr int Nn = 4096;

__device__ inline short f2bf(float f) {
    unsigned int u = __builtin_bit_cast(unsigned int, f);
    u = (u + 0x7fffu + ((u >> 16) & 1u)) >> 16;   // RNE
    return (short)u;
}
__device__ inline float bf2f(short s) {
    unsigned int u = ((unsigned int)(unsigned short)s) << 16;
    return __builtin_bit_cast(float, u);
}

__device__ inline void gl_lds16(const short* g, short* l) {
    // async global->LDS, 16 B/lane; LDS dest = wave-uniform base + lane*16
    __builtin_amdgcn_global_load_lds((const unsigned int*)g, (unsigned int*)l, 16, 0, 0);
}

// 32x32x16 bf16 MFMA layouts (m74/m101-verified C/D; A/B symmetric k-map):
//   A[m=lane&31][k=(lane>>5)*8+j]   B[k=(lane>>5)*8+j][n=lane&31]
//   C/D: col=lane&31, row=(r&3)+8*(r>>2)+4*(lane>>5)

// W8 chunked fragment: row in [0,256), kc = chunk index (8 k elems each)
#define WFRAG(Wm, row, kc) (*(const s16x8*)&(Wm)[(size_t)(kc)*2048 + (size_t)(row)*8])

// ---------------------------------------------------------------- wcvt
// fp32 [o][c] -> bf16 chunked W8[c>>3][o][c&7]
__global__ __launch_bounds__(256, 4) void wcvt_kernel(
    const float* __restrict__ wq, const float* __restrict__ wk,
    const float* __restrict__ wv, const float* __restrict__ wp,
    short* __restrict__ W)
{
    const int m = blockIdx.y;
    const float* src = (m == 0) ? wq : (m == 1) ? wk : (m == 2) ? wv : wp;
    const int idx = (blockIdx.x * 256 + threadIdx.x) * 8;
    const int o = idx >> 8, c0 = idx & 255;
    float4 a = *(const float4*)(src + idx);
    float4 b = *(const float4*)(src + idx + 4);
    s16x8 p = { f2bf(a.x), f2bf(a.y), f2bf(a.z), f2bf(a.w),
                f2bf(b.x), f2bf(b.y), f2bf(b.z), f2bf(b.w) };
    *(s16x8*)(W + m * 65536 + ((size_t)(c0 >> 3) * 256 + o) * 8) = p;
}

// ---------------------------------------------------------------- qkv (K,V only)
// grid (64 n-tiles, 4 b, 2 mat), 256 thr. LDS xT tile 33.8 KB -> 4 blocks/CU.
__global__ __launch_bounds__(256, 4) void qkv_kernel(
    const float* __restrict__ x, const short* __restrict__ W,
    const float* __restrict__ bk, const float* __restrict__ bv,
    short* __restrict__ KT, short* __restrict__ V)
{
    const int nt = blockIdx.x, b = blockIdx.y, mat = blockIdx.z;  // 0=K 1=V
    const int n0 = nt * 64;
    const short* Wm = W + (mat + 1) * 65536;       // Wk at slot 1, Wv at slot 2
    const float* bias = (mat == 0) ? bk : bv;
    const int t = threadIdx.x, lane = t & 63, wid = t >> 6, h = lane >> 5, l31 = lane & 31;

    __shared__ alignas(16) short xT[64][264];      // x^T tile [n][c] bf16

    const float* xb = x + (size_t)b * Cc * Nn;
    #pragma unroll
    for (int r = 0; r < 16; ++r) {                 // transpose+cvt 64n x 256c
        int g = r * 256 + t;
        int n = g & 63, cg = g >> 6;
        float f0 = xb[(size_t)(4*cg + 0) * Nn + n0 + n];
        float f1 = xb[(size_t)(4*cg + 1) * Nn + n0 + n];
        float f2 = xb[(size_t)(4*cg + 2) * Nn + n0 + n];
        float f3 = xb[(size_t)(4*cg + 3) * Nn + n0 + n];
        s16x4 p = { f2bf(f0), f2bf(f1), f2bf(f2), f2bf(f3) };
        *(s16x4*)&xT[n][4*cg] = p;
    }
    __syncthreads();

    f32x16 acc[4];
    #pragma unroll
    for (int s = 0; s < 4; ++s)
        #pragma unroll
        for (int r = 0; r < 16; ++r) acc[s][r] = 0.f;

    if (mat == 0) {
        // K: D[n][o] = sum_c xT[n][c] w[o][c]   (A = xT LDS, B = W8 chunked)
        const int mw = wid & 1, nwb = (wid >> 1) * 4;
        #pragma unroll 4
        for (int kk = 0; kk < 16; ++kk) {
            s16x8 a = *(const s16x8*)&xT[mw*32 + l31][kk*16 + h*8];
            #pragma unroll
            for (int s = 0; s < 4; ++s) {
                s16x8 bb = WFRAG(Wm, (nwb + s)*32 + l31, kk*2 + h);
                acc[s] = MFMA32(a, bb, acc[s]);
            }
        }
        short* dst = KT + (size_t)b * Nn * Cc;     // row layout [n][c] for gl_lds
        #pragma unroll
        for (int s = 0; s < 4; ++s) {
            int o = (nwb + s)*32 + l31;
            float bia = bias[o];
            #pragma unroll
            for (int r = 0; r < 16; ++r) {
                int n = mw*32 + (r & 3) + 8*(r >> 2) + 4*h;
                dst[(size_t)(n0 + n) * Cc + o] = f2bf(acc[s][r] + bia);
            }
        }
    } else {
        // V: D[o][n] = sum_c w[o][c] xT[n][c]   (A = W8 chunked, B = xT LDS)
        #pragma unroll 4
        for (int kk = 0; kk < 16; ++kk) {
            s16x8 a0 = WFRAG(Wm, (wid*2 + 0)*32 + l31, kk*2 + h);
            s16x8 a1 = WFRAG(Wm, (wid*2 + 1)*32 + l31, kk*2 + h);
            s16x8 b0 = *(const s16x8*)&xT[ 0 + l31][kk*16 + h*8];
            s16x8 b1 = *(const s16x8*)&xT[32 + l31][kk*16 + h*8];
            acc[0] = MFMA32(a0, b0, acc[0]);
            acc[1] = MFMA32(a0, b1, acc[1]);
            acc[2] = MFMA32(a1, b0, acc[2]);
            acc[3] = MFMA32(a1, b1, acc[3]);
        }
        // V8[j>>3][c][j&7] chunked store
        short* dst = V + (size_t)b * Cc * Nn;
        #pragma unroll
        for (int sub = 0; sub < 4; ++sub) {
            int mc = sub >> 1, nc = sub & 1;
            int j = n0 + nc*32 + l31;
            #pragma unroll
            for (int r = 0; r < 16; ++r) {
                int o = (wid*2 + mc)*32 + (r & 3) + 8*(r >> 2) + 4*h;
                dst[((size_t)(j >> 3) * 256 + o) * 8 + (j & 7)] = f2bf(acc[sub][r] + bias[o]);
            }
        }
    }
}

// ---------------------------------------------------------------- attn (split-K half)
// 512 blocks: b=(bid&7)>>1, half=(bid>>3)&1, qt=((bid>>4)<<1)|(bid&1).
// Each block: 64 q-rows x K-tiles [half*32, half*32+32). LDS = Ks 64KB +
// Ps 16KB (granule-XOR swizzled) = 81920 B exactly -> 2 blocks/CU.
// Pipeline = r12 with 34 windows; barriers producer 34 / consumer 34.
// Ps parity: write jt at window jt+1, read at jt+2 (1 barrier apart);
// rewrite of parity p at window jt+3 > last read at jt+2 (WAR safe).
// lpart/linv alias Ps[0] bytes 0..767: written after barrier #34; last Ps[0]
// read is window 32 (barrier #33) -> safe.
__global__ __launch_bounds__(512, 4) void attn_kernel(
    const short* __restrict__ KTg, const short* __restrict__ Vg,
    const short* __restrict__ Wg, const float* __restrict__ bq,
    const float* __restrict__ xg,
    short* __restrict__ Opart, float* __restrict__ Lw)
{
    const int bid = blockIdx.x;
    const int b    = (bid & 7) >> 1;            // batch per XCD pair
    const int half = (bid >> 3) & 1;
    const int qt   = ((bid >> 4) << 1) | (bid & 1);
    const int i0 = qt * 64;
    const int tbase = half * 32;

    const int t = threadIdx.x, lane = t & 63, wid = t >> 6, h = lane >> 5, l31 = lane & 31;

    __shared__ alignas(16) short Ks[2][64][256]; // K staging, granule-swizzled
    __shared__ alignas(16) short PsB[8192];      // 2 x [64 rows x 128B], XOR-swz
    short* KsF = &Ks[0][0][0];
    char*  psc = (char*)PsB;
    float* lpart = (float*)PsB;                  // [2][64] aliased (dead Ps)
    float* linv  = (float*)PsB + 128;            // [64]

    const short* Kb = KTg + (size_t)b * Nn * Cc;  // row layout [j][c]
    const short* Vb = Vg  + (size_t)b * Cc * Nn;  // chunked V8[j>>3][c][j&7]
    const float* xb = xg + (size_t)b * Cc * Nn;

    const float SC = 0.09016844005f;            // C^-0.5 * log2(e)
    f32x16 oacc[4];

    // ---------------- prologue: compute Q[i0..i0+63][256] in-kernel
    // xT tile over Ks[0], 16B-granule XOR swizzle: g16' = g16 ^ (row&15)
    {
        short* xTp = KsF;                        // [64] rows x 512 B
        #pragma unroll
        for (int r = 0; r < 8; ++r) {            // transpose+cvt 64n x 256c
            int g = r * 512 + t;
            int n = g & 63, cg = g >> 6;         // c = 4*cg
            float f0 = xb[(size_t)(4*cg + 0) * Nn + i0 + n];
            float f1 = xb[(size_t)(4*cg + 1) * Nn + i0 + n];
            float f2 = xb[(size_t)(4*cg + 2) * Nn + i0 + n];
            float f3 = xb[(size_t)(4*cg + 3) * Nn + i0 + n];
            s16x4 p = { f2bf(f0), f2bf(f1), f2bf(f2), f2bf(f3) };
            int bcol = (((cg >> 1) ^ (n & 15)) << 4) + (cg & 1) * 8;
            *(s16x4*)((char*)xTp + n * 512 + bcol) = p;
        }
        __syncthreads();

        // Q-GEMM: D[n 0..63][o = wid*32+l31] = sum_c xT[n][c] Wq[o][c]
        const short* Wq = Wg;                    // mat 0 chunked
        f32x16 qa[2];
        #pragma unroll
        for (int s = 0; s < 2; ++s)
            #pragma unroll
            for (int r = 0; r < 16; ++r) qa[s][r] = 0.f;
        #pragma unroll 4
        for (int kk = 0; kk < 16; ++kk) {
            int gsw = ((kk*2 + h) ^ (l31 & 15)) << 4;
            s16x8 a0 = *(const s16x8*)((char*)xTp + ( 0 + l31) * 512 + gsw);
            s16x8 a1 = *(const s16x8*)((char*)xTp + (32 + l31) * 512 + gsw);
            s16x8 bb = WFRAG(Wq, wid*32 + l31, kk*2 + h);
            qa[0] = MFMA32(a0, bb, qa[0]);
            qa[1] = MFMA32(a1, bb, qa[1]);
        }
        // D + bq -> Fq (over Ks[1]), bf16, same granule swizzle
        short* Fq = KsF + 16384;
        const int o = wid*32 + l31;
        const float bo = bq[o];
        #pragma unroll
        for (int mw2 = 0; mw2 < 2; ++mw2)
            #pragma unroll
            for (int r = 0; r < 16; ++r) {
                int n = mw2*32 + (r & 3) + 8*(r >> 2) + 4*h;
                int bcol = (((o >> 3) ^ (n & 15)) << 4) + (o & 7) * 2;
                *(short*)((char*)Fq + n * 512 + bcol) = f2bf(qa[mw2][r] + bo);
            }
    }
    __syncthreads();

    if (wid < 4) {
        // ---------------- producer: S^T = K Q^T, exp, P
        const int w4 = wid, mj = w4 >> 1, ni = w4 & 1;

        s16x8 qf[16];                            // from Fq (Ks[1] area)
        {
            const short* Fq = KsF + 16384;
            const int qrow = ni*32 + l31;
            #pragma unroll
            for (int kc = 0; kc < 16; ++kc) {
                int bcol = ((kc*2 + h) ^ (qrow & 15)) << 4;
                qf[kc] = *(const s16x8*)((char*)Fq + qrow * 512 + bcol);
            }
        }
        float lacc = 0.f;
        const int rl = mj*32 + l31;             // A-frag row; (rl&31)==l31
        const int ip = ni*32 + l31;
        const int psw = ip & 7;

        for (int w = 0; w < 34; ++w) {
            if (w < 32) {                        // stage K tile tbase+w (async DMA)
                const int kb = w & 1;
                #pragma unroll
                for (int it = 0; it < 8; ++it) {
                    int r = (w4*8 + it)*2 + (lane >> 5);
                    int g = l31 ^ (r & 31);
                    const short* gp = Kb + (size_t)((tbase + w)*64 + r) * Cc + g*8;
                    short* lp = KsF + kb*16384 + (w4*8 + it)*512;  // wave-uniform
                    gl_lds16(gp, lp);
                }
            }
            if (w >= 1 && w < 33) {
                const int jt = w - 1, kb = jt & 1;
                const short* abase = KsF + kb*16384 + rl*256;
                f32x16 s0, s1;
                #pragma unroll
                for (int r = 0; r < 16; ++r) { s0[r] = 0.f; s1[r] = 0.f; }
                #pragma unroll
                for (int kc = 0; kc < 8; ++kc) {
                    s16x8 a0 = *(const s16x8*)(abase + (((kc*4 + 0 + h) ^ l31) << 3));
                    s16x8 a1 = *(const s16x8*)(abase + (((kc*4 + 2 + h) ^ l31) << 3));
                    s0 = MFMA32(a0, qf[2*kc + 0], s0);
                    s1 = MFMA32(a1, qf[2*kc + 1], s1);
                }
                float ps[16], lsum = 0.f;
                #pragma unroll
                for (int r = 0; r < 16; ++r) {
                    float e = exp2f((s0[r] + s1[r]) * SC);
                    ps[r] = e; lsum += e;
                }
                lsum += __shfl_xor(lsum, 32);
                lacc += lsum;
                // Ps write, granule-XOR swizzled (granule = mj*4+g, +8h bytes)
                char* pw = psc + kb*8192 + ip*128 + 8*h;
                #pragma unroll
                for (int g = 0; g < 4; ++g) {
                    s16x4 pk = { f2bf(ps[4*g+0]), f2bf(ps[4*g+1]),
                                 f2bf(ps[4*g+2]), f2bf(ps[4*g+3]) };
                    *(s16x4*)(pw + ((((mj<<2) + g) ^ psw) << 4)) = pk;
                }
            }
            __syncthreads();                     // producer: full drain
        }
        if (h == 0) lpart[mj*64 + ip] = lacc;
    } else {
        // ---------------- consumer: O^T[c][i] += V[c][j] P[i][j]
        const int w2 = wid - 4;
        #pragma unroll
        for (int s = 0; s < 4; ++s)
            #pragma unroll
            for (int r = 0; r < 16; ++r) oacc[s][r] = 0.f;

        s16x8 vA[8], vB[8];
        const short* vc0 = Vb + (size_t)(w2*64 +  0 + l31) * 8 + h*2048;
        const short* vc1 = Vb + (size_t)(w2*64 + 32 + l31) * 8 + h*2048;
        const int psw = l31 & 7;

        for (int tp = 0; tp < 17; ++tp) {
            const int w0 = tp*2, w1 = w0 + 1;
            // even window w0: issue V tile tbase+w0-1 -> vA ; consume jt=w0-2 from vB
            if (w0 >= 1 && w0 <= 32) {
                const size_t jc = (size_t)(tbase + w0 - 1) * 8;   // j0>>3
                #pragma unroll
                for (int kj = 0; kj < 4; ++kj) {
                    vA[kj]   = *(const s16x8*)(vc0 + (jc + kj*2) * 2048);
                    vA[4+kj] = *(const s16x8*)(vc1 + (jc + kj*2) * 2048);
                }
            }
            if (w0 >= 2) {
                const int pb = (w0 - 2) & 1;
                const char* pr0 = psc + pb*8192 + l31*128;
                s16x8 p0[4], p1[4];
                #pragma unroll
                for (int kj = 0; kj < 4; ++kj) {
                    int go = ((kj*2 + h) ^ psw) << 4;
                    p0[kj] = *(const s16x8*)(pr0 + go);
                    p1[kj] = *(const s16x8*)(pr0 + 4096 + go);   // rows 32..63
                }
                #pragma unroll
                for (int kj = 0; kj < 4; ++kj) {
                    oacc[0] = MFMA32(vB[kj],   p0[kj], oacc[0]);
                    oacc[1] = MFMA32(vB[kj],   p1[kj], oacc[1]);
                    oacc[2] = MFMA32(vB[4+kj], p0[kj], oacc[2]);
                    oacc[3] = MFMA32(vB[4+kj], p1[kj], oacc[3]);
                }
            }
            asm volatile("s_barrier" ::: "memory");   // no drain: V stays in flight
            // odd window w1: issue V tile tbase+w1-1 -> vB ; consume jt=w1-2 from vA
            if (w1 <= 32) {
                const size_t jc = (size_t)(tbase + w1 - 1) * 8;
                #pragma unroll
                for (int kj = 0; kj < 4; ++kj) {
                    vB[kj]   = *(const s16x8*)(vc0 + (jc + kj*2) * 2048);
                    vB[4+kj] = *(const s16x8*)(vc1 + (jc + kj*2) * 2048);
                }
            }
            if (w1 >= 2 && w1 < 34) {
                const int pb = (w1 - 2) & 1;
                const char* pr0 = psc + pb*8192 + l31*128;
                s16x8 p0[4], p1[4];
                #pragma unroll
                for (int kj = 0; kj < 4; ++kj) {
                    int go = ((kj*2 + h) ^ psw) << 4;
                    p0[kj] = *(const s16x8*)(pr0 + go);
                    p1[kj] = *(const s16x8*)(pr0 + 4096 + go);
                }
                #pragma unroll
                for (int kj = 0; kj < 4; ++kj) {
                    oacc[0] = MFMA32(vA[kj],   p0[kj], oacc[0]);
                    oacc[1] = MFMA32(vA[kj],   p1[kj], oacc[1]);
                    oacc[2] = MFMA32(vA[4+kj], p0[kj], oacc[2]);
                    oacc[3] = MFMA32(vA[4+kj], p1[kj], oacc[3]);
                }
            }
            asm volatile("s_barrier" ::: "memory");
        }
    }

    // ---------------- epilogue: normalize by local l, T-bounce, store O-hat + l
    __syncthreads();
    const size_t slot = (((size_t)b*64 + qt)*2 + half);
    if (t < 64) {
        float s = lpart[t] + lpart[64 + t];
        linv[t] = 1.0f / s;
        Lw[(slot << 6) + t] = s;
    }
    __syncthreads();
    short (*T)[264] = (short(*)[264])KsF;       // scratch over Ks
    if (wid >= 4) {
        const int w2 = wid - 4;
        #pragma unroll
        for (int sub = 0; sub < 4; ++sub) {
            int mc = sub >> 1, nc = sub & 1;
            int ip = nc*32 + l31;
            float rl2 = linv[ip];
            #pragma unroll
            for (int r = 0; r < 16; ++r) {
                int c = w2*64 + mc*32 + (r & 3) + 8*(r >> 2) + 4*h;
                T[ip][c] = f2bf(oacc[sub][r] * rl2);
            }
        }
    }
    __syncthreads();
    short* Od = Opart + (slot << 14);           // [64 i][256 c] bf16 = 32KB
    #pragma unroll
    for (int r = 0; r < 8; ++r) {
        int i = r*8 + (t >> 6), c4 = (t & 63) * 4;
        *(s16x4*)&Od[i*256 + c4] = *(const s16x4*)&T[i][c4];
    }
}

// ---------------------------------------------------------------- proj (combine)
// grid (64 qt, 4 b), 512 thr. Blend the two K-halves' locally-normalized
// O-hats with w = l0/(l0+l1), then the r12 proj+residual epilogue verbatim.
__global__ __launch_bounds__(512, 2) void proj_kernel(
    const short* __restrict__ Opart, const float* __restrict__ Lw,
    const short* __restrict__ Wg, const float* __restrict__ bp,
    const float* __restrict__ xg, float* __restrict__ outg)
{
    const int qt = blockIdx.x, b = blockIdx.y;
    const int i0 = qt * 64;
    const int t = threadIdx.x, lane = t & 63, wid = t >> 6, h = lane >> 5, l31 = lane & 31;

    __shared__ alignas(16) short scr[32768];     // 64KB: T then F
    short (*T)[264] = (short(*)[264])scr;

    const size_t slot = ((size_t)b*64 + qt)*2;
    const short* O0 = Opart + (slot << 14);
    const short* O1 = Opart + ((slot + 1) << 14);
    const float* L0 = Lw + (slot << 6);
    const float* L1 = Lw + ((slot + 1) << 6);

    // T[i][c] = w0[i]*O0 + w1[i]*O1   (coalesced row reads, row-copy writes)
    #pragma unroll
    for (int r = 0; r < 8; ++r) {
        int i = r*8 + (t >> 6), c4 = (t & 63) * 4;
        float l0 = L0[i], l1 = L1[i];
        float w0 = l0 / (l0 + l1), w1 = 1.0f - w0;
        s16x4 a = *(const s16x4*)&O0[i*256 + c4];
        s16x4 c = *(const s16x4*)&O1[i*256 + c4];
        s16x4 o;
        #pragma unroll
        for (int k = 0; k < 4; ++k)
            o[k] = f2bf(w0 * bf2f(a[k]) + w1 * bf2f(c[k]));
        *(s16x4*)&T[i][c4] = o;
    }
    __syncthreads();

    // proj: D[n][o] = sum_c T[n][c] Wp[o][c]
    const short* Wp = Wg + 3 * 65536;
    f32x16 acc2[2];
    #pragma unroll
    for (int s = 0; s < 2; ++s)
        #pragma unroll
        for (int r = 0; r < 16; ++r) acc2[s][r] = 0.f;

    #pragma unroll 4
    for (int kk = 0; kk < 16; ++kk) {
        s16x8 a0 = *(const s16x8*)&T[ 0 + l31][kk*16 + h*8];
        s16x8 a1 = *(const s16x8*)&T[32 + l31][kk*16 + h*8];
        s16x8 bb = WFRAG(Wp, wid*32 + l31, kk*2 + h);
        acc2[0] = MFMA32(a0, bb, acc2[0]);
        acc2[1] = MFMA32(a1, bb, acc2[1]);
    }
    __syncthreads();                             // all waves done reading T

    // bounce acc2 through XOR-swizzled fp32 tile F[n][o^(n&31)]
    float (*F)[256] = (float(*)[256])scr;        // 64n x 256o fp32 = 64 KB
    {
        const int o = wid*32 + l31;
        #pragma unroll
        for (int nh = 0; nh < 2; ++nh) {
            #pragma unroll
            for (int r = 0; r < 16; ++r) {
                int n = nh*32 + (r & 3) + 8*(r >> 2) + 4*h;
                F[n][o ^ (n & 31)] = acc2[nh][r];
            }
        }
    }
    __syncthreads();

    // coalesced residual+store: lanes take consecutive n, fixed o
    const float* xb = xg + (size_t)b * Cc * Nn;
    float* ob = outg + (size_t)b * Cc * Nn;
    #pragma unroll 8
    for (int it = 0; it < 32; ++it) {
        int o = it*8 + wid;
        size_t idx = (size_t)o * Nn + i0 + lane;
        ob[idx] = xb[idx] + F[lane][o ^ (lane & 31)] + bp[o];
    }
}

// ---------------------------------------------------------------- launch
extern "C" void kernel_launch(void* const* d_in, const int* in_sizes, int n_in,
                              void* d_out, int out_size, void* d_ws, size_t ws_size,
                              hipStream_t stream)
{
    const float* x  = (const float*)d_in[0];
    const float* wq = (const float*)d_in[1];
    const float* bq = (const float*)d_in[2];
    const float* wk = (const float*)d_in[3];
    const float* bk = (const float*)d_in[4];
    const float* wv = (const float*)d_in[5];
    const float* bv = (const float*)d_in[6];
    const float* wp = (const float*)d_in[7];
    const float* bp = (const float*)d_in[8];

    const size_t elems  = (size_t)4 * Nn * Cc;          // shorts per K/V buffer
    const size_t wel    = 4 * 65536;                    // W8 shorts
    const size_t oel    = (size_t)512 * 16384;          // Opart shorts (16 MiB)
    const size_t need   = (2*elems + wel + oel) * sizeof(short)
                        + (size_t)512 * 64 * sizeof(float);   // ~32.6 MiB
    if (ws_size < need) return;
    short* KT    = (short*)d_ws;               // [b][n][c] bf16
    short* V     = KT + elems;                 // [b] chunked V8[j>>3][c][j&7]
    short* Wbf   = V + elems;                  // 4 x chunked W8[c>>3][o][c&7]
    short* Opart = Wbf + wel;                  // 512 x [64][256] bf16
    float* Lw    = (float*)(Opart + oel);      // 512 x [64] fp32
    (void)in_sizes; (void)n_in; (void)out_size;

    wcvt_kernel<<<dim3(32, 4), 256, 0, stream>>>(wq, wk, wv, wp, Wbf);
    qkv_kernel<<<dim3(64, 4, 2), 256, 0, stream>>>(x, Wbf, bk, bv, KT, V);
    attn_kernel<<<dim3(512), 512, 0, stream>>>(KT, V, Wbf, bq, x, Opart, Lw);
    proj_kernel<<<dim3(64, 4), 512, 0, stream>>>(Opart, Lw, Wbf, bp, x, (float*)d_out);
}

// Round 10
// 222.694 us; speedup vs baseline: 1.0940x; 1.0940x over previous
//
#include <hip/hip_runtime.h>
#include <hip/hip_bf16.h>

// NonLocalBlock B=4,C=256,H=W=64 (N=4096) — round 14.
//  Mechanism: amortize the per-window fixed overhead (r12 null + r13 worse
//  => windows carry ~2.5k cy of barrier/drain/fill cost regardless of work).
//  Each attn block now does 128 q-rows x half-K: windows 66 -> 34, work per
//  window 2x (K A-frags shared across both i-halves -> ds_reads UNchanged),
//  grid stays 256 = 1 block/CU (r13 showed 2 blocks/CU contend, not overlap).
//  Split-K combine (r13's proven blend) runs in the proj kernel.
//  qkv/wcvt identical to r12. Ps padded (known-good), raw consumer barriers.
// ws = KT | V8 | W8 | Opart | Lw = 34.2 MiB (same as r13, verified fits).

typedef __attribute__((ext_vector_type(4))) short s16x4;
typedef __attribute__((ext_vector_type(8))) short s16x8;
typedef __attribute__((ext_vector_type(16))) float f32x16;

#define MFMA32(a, b, c) __builtin_amdgcn_mfma_f32_32x32x16_bf16((a), (b), (c), 0, 0, 0)

constexpr int Cc = 256;
constexpr int Nn = 4096;

__device__ inline short f2bf(float f) {
    unsigned int u = __builtin_bit_cast(unsigned int, f);
    u = (u + 0x7fffu + ((u >> 16) & 1u)) >> 16;   // RNE
    return (short)u;
}
__device__ inline float bf2f(short s) {
    unsigned int u = ((unsigned int)(unsigned short)s) << 16;
    return __builtin_bit_cast(float, u);
}

__device__ inline void gl_lds16(const short* g, short* l) {
    __builtin_amdgcn_global_load_lds((const unsigned int*)g, (unsigned int*)l, 16, 0, 0);
}

// 32x32x16 bf16 MFMA layouts (m74/m101-verified C/D; A/B symmetric k-map):
//   A[m=lane&31][k=(lane>>5)*8+j]   B[k=(lane>>5)*8+j][n=lane&31]
//   C/D: col=lane&31, row=(r&3)+8*(r>>2)+4*(lane>>5)

#define WFRAG(Wm, row, kc) (*(const s16x8*)&(Wm)[(size_t)(kc)*2048 + (size_t)(row)*8])

// ---------------------------------------------------------------- wcvt
__global__ __launch_bounds__(256, 4) void wcvt_kernel(
    const float* __restrict__ wq, const float* __restrict__ wk,
    const float* __restrict__ wv, const float* __restrict__ wp,
    short* __restrict__ W)
{
    const int m = blockIdx.y;
    const float* src = (m == 0) ? wq : (m == 1) ? wk : (m == 2) ? wv : wp;
    const int idx = (blockIdx.x * 256 + threadIdx.x) * 8;
    const int o = idx >> 8, c0 = idx & 255;
    float4 a = *(const float4*)(src + idx);
    float4 b = *(const float4*)(src + idx + 4);
    s16x8 p = { f2bf(a.x), f2bf(a.y), f2bf(a.z), f2bf(a.w),
                f2bf(b.x), f2bf(b.y), f2bf(b.z), f2bf(b.w) };
    *(s16x8*)(W + m * 65536 + ((size_t)(c0 >> 3) * 256 + o) * 8) = p;
}

// ---------------------------------------------------------------- qkv (K,V only; r12 verbatim)
__global__ __launch_bounds__(256, 4) void qkv_kernel(
    const float* __restrict__ x, const short* __restrict__ W,
    const float* __restrict__ bk, const float* __restrict__ bv,
    short* __restrict__ KT, short* __restrict__ V)
{
    const int nt = blockIdx.x, b = blockIdx.y, mat = blockIdx.z;  // 0=K 1=V
    const int n0 = nt * 64;
    const short* Wm = W + (mat + 1) * 65536;
    const float* bias = (mat == 0) ? bk : bv;
    const int t = threadIdx.x, lane = t & 63, wid = t >> 6, h = lane >> 5, l31 = lane & 31;

    __shared__ alignas(16) short xT[64][264];

    const float* xb = x + (size_t)b * Cc * Nn;
    #pragma unroll
    for (int r = 0; r < 16; ++r) {
        int g = r * 256 + t;
        int n = g & 63, cg = g >> 6;
        float f0 = xb[(size_t)(4*cg + 0) * Nn + n0 + n];
        float f1 = xb[(size_t)(4*cg + 1) * Nn + n0 + n];
        float f2 = xb[(size_t)(4*cg + 2) * Nn + n0 + n];
        float f3 = xb[(size_t)(4*cg + 3) * Nn + n0 + n];
        s16x4 p = { f2bf(f0), f2bf(f1), f2bf(f2), f2bf(f3) };
        *(s16x4*)&xT[n][4*cg] = p;
    }
    __syncthreads();

    f32x16 acc[4];
    #pragma unroll
    for (int s = 0; s < 4; ++s)
        #pragma unroll
        for (int r = 0; r < 16; ++r) acc[s][r] = 0.f;

    if (mat == 0) {
        const int mw = wid & 1, nwb = (wid >> 1) * 4;
        #pragma unroll 4
        for (int kk = 0; kk < 16; ++kk) {
            s16x8 a = *(const s16x8*)&xT[mw*32 + l31][kk*16 + h*8];
            #pragma unroll
            for (int s = 0; s < 4; ++s) {
                s16x8 bb = WFRAG(Wm, (nwb + s)*32 + l31, kk*2 + h);
                acc[s] = MFMA32(a, bb, acc[s]);
            }
        }
        short* dst = KT + (size_t)b * Nn * Cc;
        #pragma unroll
        for (int s = 0; s < 4; ++s) {
            int o = (nwb + s)*32 + l31;
            float bia = bias[o];
            #pragma unroll
            for (int r = 0; r < 16; ++r) {
                int n = mw*32 + (r & 3) + 8*(r >> 2) + 4*h;
                dst[(size_t)(n0 + n) * Cc + o] = f2bf(acc[s][r] + bia);
            }
        }
    } else {
        #pragma unroll 4
        for (int kk = 0; kk < 16; ++kk) {
            s16x8 a0 = WFRAG(Wm, (wid*2 + 0)*32 + l31, kk*2 + h);
            s16x8 a1 = WFRAG(Wm, (wid*2 + 1)*32 + l31, kk*2 + h);
            s16x8 b0 = *(const s16x8*)&xT[ 0 + l31][kk*16 + h*8];
            s16x8 b1 = *(const s16x8*)&xT[32 + l31][kk*16 + h*8];
            acc[0] = MFMA32(a0, b0, acc[0]);
            acc[1] = MFMA32(a0, b1, acc[1]);
            acc[2] = MFMA32(a1, b0, acc[2]);
            acc[3] = MFMA32(a1, b1, acc[3]);
        }
        short* dst = V + (size_t)b * Cc * Nn;
        #pragma unroll
        for (int sub = 0; sub < 4; ++sub) {
            int mc = sub >> 1, nc = sub & 1;
            int j = n0 + nc*32 + l31;
            #pragma unroll
            for (int r = 0; r < 16; ++r) {
                int o = (wid*2 + mc)*32 + (r & 3) + 8*(r >> 2) + 4*h;
                dst[((size_t)(j >> 3) * 256 + o) * 8 + (j & 7)] = f2bf(acc[sub][r] + bias[o]);
            }
        }
    }
}

// ---------------------------------------------------------------- attn (128 q-rows x half-K)
// grid 256 = 1 block/CU. bid: b=(bid&7)>>1, half=(bid>>3)&1,
// qt=((bid>>4)<<1)|(bid&1) in [0,32). 34 windows; producer waves 0-3 each
// compute S^T[32j][32i] for TWO i-blocks (ni, ni+2) sharing the SAME K
// A-frags (ds_reads unchanged vs r12); consumer waves 4-7 hold oacc[8]
// (4 i-blocks x 2 c-halves). Ps[2][128][72] padded. Raw consumer barriers.
// LDS: Ks 64K | Ps 36,864 | lpart 1K | linv 512 = 103,936 B.
__global__ __launch_bounds__(512, 2) void attn_kernel(
    const short* __restrict__ KTg, const short* __restrict__ Vg,
    const short* __restrict__ Wg, const float* __restrict__ bq,
    const float* __restrict__ xg,
    short* __restrict__ Opart, float* __restrict__ Lw)
{
    const int bid = blockIdx.x;
    const int b    = (bid & 7) >> 1;
    const int half = (bid >> 3) & 1;
    const int qt   = ((bid >> 4) << 1) | (bid & 1);   // [0,32)
    const int i0 = qt * 128;
    const int tbase = half * 32;

    const int t = threadIdx.x, lane = t & 63, wid = t >> 6, h = lane >> 5, l31 = lane & 31;

    __shared__ alignas(16) char LDS[103936];
    short* KsB = (short*)LDS;                               // [2][64][256] = 64KB
    short (*Ps)[128][72] = (short(*)[128][72])(LDS + 65536); // 36,864B
    float* lpartF = (float*)(LDS + 102400);                 // [2][128]
    float* linv   = (float*)(LDS + 103424);                 // [128]

    const short* Kb = KTg + (size_t)b * Nn * Cc;   // [j][c]
    const short* Vb = Vg  + (size_t)b * Cc * Nn;   // chunked V8[j>>3][c][j&7]
    const float* xb = xg + (size_t)b * Cc * Nn;

    const float SC = 0.09016844005f;               // C^-0.5 * log2(e)
    f32x16 oacc[8];

    // ---------------- prologue: Q[i0..i0+127][256] in-kernel
    {
        short* xTp = KsB;                          // 128 rows x 512B = 64KB
        #pragma unroll
        for (int r = 0; r < 16; ++r) {
            int g = r * 512 + t;
            int n = g & 127, cg = g >> 7;          // c = 4*cg
            float f0 = xb[(size_t)(4*cg + 0) * Nn + i0 + n];
            float f1 = xb[(size_t)(4*cg + 1) * Nn + i0 + n];
            float f2 = xb[(size_t)(4*cg + 2) * Nn + i0 + n];
            float f3 = xb[(size_t)(4*cg + 3) * Nn + i0 + n];
            s16x4 p = { f2bf(f0), f2bf(f1), f2bf(f2), f2bf(f3) };
            int bcol = (((cg >> 1) ^ (n & 15)) << 4) + (cg & 1) * 8;
            *(s16x4*)((char*)xTp + n * 512 + bcol) = p;
        }
        __syncthreads();

        const short* Wq = Wg;
        f32x16 qa[4];
        #pragma unroll
        for (int s = 0; s < 4; ++s)
            #pragma unroll
            for (int r = 0; r < 16; ++r) qa[s][r] = 0.f;
        #pragma unroll 4
        for (int kk = 0; kk < 16; ++kk) {
            s16x8 bb = WFRAG(Wq, wid*32 + l31, kk*2 + h);
            int gsw = ((kk*2 + h) ^ (l31 & 15)) << 4;
            #pragma unroll
            for (int nb = 0; nb < 4; ++nb) {
                s16x8 aa = *(const s16x8*)((char*)xTp + (nb*32 + l31) * 512 + gsw);
                qa[nb] = MFMA32(aa, bb, qa[nb]);
            }
        }
        __syncthreads();                           // xTp reads done before overwrite

        short* Fq = KsB;                           // Fq reuses the same 64KB
        const int o = wid*32 + l31;
        const float bo = bq[o];
        #pragma unroll
        for (int nb = 0; nb < 4; ++nb)
            #pragma unroll
            for (int r = 0; r < 16; ++r) {
                int n = nb*32 + (r & 3) + 8*(r >> 2) + 4*h;
                int bcol = (((o >> 3) ^ (n & 15)) << 4) + (o & 7) * 2;
                *(short*)((char*)Fq + n * 512 + bcol) = f2bf(qa[nb][r] + bo);
            }
    }
    __syncthreads();

    s16x8 qfA[16], qfB[16];                        // producer Q frags (2 i-blocks)
    if (wid < 4) {
        const short* Fq = KsB;
        const int ni = wid & 1;
        const int qrA = ni*32 + l31, qrB = (ni + 2)*32 + l31;
        #pragma unroll
        for (int kc = 0; kc < 16; ++kc) {
            qfA[kc] = *(const s16x8*)((char*)Fq + qrA * 512 + (((kc*2 + h) ^ (qrA & 15)) << 4));
            qfB[kc] = *(const s16x8*)((char*)Fq + qrB * 512 + (((kc*2 + h) ^ (qrB & 15)) << 4));
        }
    }
    __syncthreads();                               // qf in regs before Ks staging overwrites Fq

    if (wid < 4) {
        // ---------------- producer
        const int w4 = wid, mj = w4 >> 1, ni = w4 & 1;
        float lacc0 = 0.f, lacc1 = 0.f;
        const int rl = mj*32 + l31;
        const int ipA = ni*32 + l31, ipB = (ni + 2)*32 + l31;

        for (int w = 0; w < 34; ++w) {
            if (w < 32) {                          // stage K tile tbase+w
                const int kb = w & 1;
                #pragma unroll
                for (int it = 0; it < 8; ++it) {
                    int r = (w4*8 + it)*2 + (lane >> 5);
                    int g = l31 ^ (r & 31);
                    const short* gp = Kb + (size_t)((tbase + w)*64 + r) * Cc + g*8;
                    short* lp = KsB + kb*16384 + (w4*8 + it)*512;
                    gl_lds16(gp, lp);
                }
            }
            if (w >= 1 && w < 33) {
                const int jt = w - 1, kb = jt & 1;
                const short* abase = KsB + kb*16384 + rl*256;
                f32x16 s0A, s1A, s0B, s1B;
                #pragma unroll
                for (int r = 0; r < 16; ++r) { s0A[r]=0.f; s1A[r]=0.f; s0B[r]=0.f; s1B[r]=0.f; }
                #pragma unroll
                for (int kc = 0; kc < 8; ++kc) {   // K A-frags shared by both i-blocks
                    s16x8 a0 = *(const s16x8*)(abase + (((kc*4 + 0 + h) ^ l31) << 3));
                    s16x8 a1 = *(const s16x8*)(abase + (((kc*4 + 2 + h) ^ l31) << 3));
                    s0A = MFMA32(a0, qfA[2*kc + 0], s0A);
                    s1A = MFMA32(a1, qfA[2*kc + 1], s1A);
                    s0B = MFMA32(a0, qfB[2*kc + 0], s0B);
                    s1B = MFMA32(a1, qfB[2*kc + 1], s1B);
                }
                {   // softmax + Ps, i-block A
                    float ps[16], ls = 0.f;
                    #pragma unroll
                    for (int r = 0; r < 16; ++r) {
                        float e = exp2f((s0A[r] + s1A[r]) * SC);
                        ps[r] = e; ls += e;
                    }
                    ls += __shfl_xor(ls, 32);
                    lacc0 += ls;
                    #pragma unroll
                    for (int g = 0; g < 4; ++g) {
                        s16x4 pk = { f2bf(ps[4*g+0]), f2bf(ps[4*g+1]),
                                     f2bf(ps[4*g+2]), f2bf(ps[4*g+3]) };
                        *(s16x4*)&Ps[kb][ipA][mj*32 + g*8 + 4*h] = pk;
                    }
                }
                {   // softmax + Ps, i-block B
                    float ps[16], ls = 0.f;
                    #pragma unroll
                    for (int r = 0; r < 16; ++r) {
                        float e = exp2f((s0B[r] + s1B[r]) * SC);
                        ps[r] = e; ls += e;
                    }
                    ls += __shfl_xor(ls, 32);
                    lacc1 += ls;
                    #pragma unroll
                    for (int g = 0; g < 4; ++g) {
                        s16x4 pk = { f2bf(ps[4*g+0]), f2bf(ps[4*g+1]),
                                     f2bf(ps[4*g+2]), f2bf(ps[4*g+3]) };
                        *(s16x4*)&Ps[kb][ipB][mj*32 + g*8 + 4*h] = pk;
                    }
                }
            }
            __syncthreads();
        }
        if (h == 0) {
            lpartF[mj*128 + ipA] = lacc0;
            lpartF[mj*128 + ipB] = lacc1;
        }
    } else {
        // ---------------- consumer: O^T[c][i] += V[c][j] P[i][j], 4 i-blocks
        const int w2 = wid - 4;
        #pragma unroll
        for (int s = 0; s < 8; ++s)
            #pragma unroll
            for (int r = 0; r < 16; ++r) oacc[s][r] = 0.f;

        s16x8 vA[8], vB[8];
        const short* vc0 = Vb + (size_t)(w2*64 +  0 + l31) * 8 + h*2048;
        const short* vc1 = Vb + (size_t)(w2*64 + 32 + l31) * 8 + h*2048;

        for (int tp = 0; tp < 17; ++tp) {
            const int w0 = tp*2, w1 = w0 + 1;
            if (w0 >= 1 && w0 <= 32) {
                const size_t jc = (size_t)(tbase + w0 - 1) * 8;
                #pragma unroll
                for (int kj = 0; kj < 4; ++kj) {
                    vA[kj]   = *(const s16x8*)(vc0 + (jc + kj*2) * 2048);
                    vA[4+kj] = *(const s16x8*)(vc1 + (jc + kj*2) * 2048);
                }
            }
            if (w0 >= 2) {
                const int pb = (w0 - 2) & 1;
                #pragma unroll
                for (int ib = 0; ib < 4; ++ib) {
                    s16x8 pf[4];
                    #pragma unroll
                    for (int kj = 0; kj < 4; ++kj)
                        pf[kj] = *(const s16x8*)&Ps[pb][ib*32 + l31][kj*16 + h*8];
                    #pragma unroll
                    for (int kj = 0; kj < 4; ++kj) {
                        oacc[ib*2+0] = MFMA32(vB[kj],   pf[kj], oacc[ib*2+0]);
                        oacc[ib*2+1] = MFMA32(vB[4+kj], pf[kj], oacc[ib*2+1]);
                    }
                }
            }
            asm volatile("s_barrier" ::: "memory");
            if (w1 <= 32) {
                const size_t jc = (size_t)(tbase + w1 - 1) * 8;
                #pragma unroll
                for (int kj = 0; kj < 4; ++kj) {
                    vB[kj]   = *(const s16x8*)(vc0 + (jc + kj*2) * 2048);
                    vB[4+kj] = *(const s16x8*)(vc1 + (jc + kj*2) * 2048);
                }
            }
            if (w1 >= 2 && w1 < 34) {
                const int pb = (w1 - 2) & 1;
                #pragma unroll
                for (int ib = 0; ib < 4; ++ib) {
                    s16x8 pf[4];
                    #pragma unroll
                    for (int kj = 0; kj < 4; ++kj)
                        pf[kj] = *(const s16x8*)&Ps[pb][ib*32 + l31][kj*16 + h*8];
                    #pragma unroll
                    for (int kj = 0; kj < 4; ++kj) {
                        oacc[ib*2+0] = MFMA32(vA[kj],   pf[kj], oacc[ib*2+0]);
                        oacc[ib*2+1] = MFMA32(vA[4+kj], pf[kj], oacc[ib*2+1]);
                    }
                }
            }
            asm volatile("s_barrier" ::: "memory");
        }
    }

    // ---------------- epilogue: local-normalize, T, store O-hat + l
    __syncthreads();
    const size_t slot = (((size_t)b*32 + qt)*2 + half);
    if (t < 128) {
        float s = lpartF[t] + lpartF[128 + t];
        linv[t] = 1.0f / s;
        Lw[(slot << 7) + t] = s;
    }
    __syncthreads();
    short (*T)[264] = (short(*)[264])LDS;          // 128 x 264 = 67,584B (< lpart)
    if (wid >= 4) {
        const int w2 = wid - 4;
        #pragma unroll
        for (int ib = 0; ib < 4; ++ib) {
            int ip = ib*32 + l31;
            float rl2 = linv[ip];
            #pragma unroll
            for (int ch = 0; ch < 2; ++ch)
                #pragma unroll
                for (int r = 0; r < 16; ++r) {
                    int c = w2*64 + ch*32 + (r & 3) + 8*(r >> 2) + 4*h;
                    T[ip][c] = f2bf(oacc[ib*2+ch][r] * rl2);
                }
        }
    }
    __syncthreads();
    short* Od = Opart + (slot << 15);              // [128][256] bf16 = 64KB
    #pragma unroll
    for (int r = 0; r < 16; ++r) {
        int i = r*8 + (t >> 6), c4 = (t & 63) * 4;
        *(s16x4*)&Od[i*256 + c4] = *(const s16x4*)&T[i][c4];
    }
}

// ---------------------------------------------------------------- proj (combine + proj + residual)
// grid (64 q64-tiles, 4 b), 512 thr. Blend the two K-halves' O-hats with
// w = l0/(l0+l1) over this block's 64 rows, then r12's proj+residual.
__global__ __launch_bounds__(512, 2) void proj_kernel(
    const short* __restrict__ Opart, const float* __restrict__ Lw,
    const short* __restrict__ Wg, const float* __restrict__ bp,
    const float* __restrict__ xg, float* __restrict__ outg)
{
    const int q64 = blockIdx.x, b = blockIdx.y;
    const int i0 = q64 * 64;
    const int qt = q64 >> 1, roff = (q64 & 1) * 64;
    const int t = threadIdx.x, lane = t & 63, wid = t >> 6, h = lane >> 5, l31 = lane & 31;

    __shared__ alignas(16) short scr[32768];       // 64KB: T then F
    short (*T)[264] = (short(*)[264])scr;

    const size_t s2 = ((size_t)b*32 + qt) * 2;
    const short* O0 = Opart + (s2 << 15);
    const short* O1 = O0 + 32768;
    const float* L0 = Lw + (s2 << 7);
    const float* L1 = L0 + 128;

    #pragma unroll
    for (int r = 0; r < 8; ++r) {
        int i = r*8 + (t >> 6), c4 = (t & 63) * 4;
        int ig = roff + i;
        float l0 = L0[ig], l1 = L1[ig];
        float w0 = l0 / (l0 + l1), w1 = 1.0f - w0;
        s16x4 a = *(const s16x4*)&O0[ig*256 + c4];
        s16x4 c = *(const s16x4*)&O1[ig*256 + c4];
        s16x4 o;
        #pragma unroll
        for (int k = 0; k < 4; ++k)
            o[k] = f2bf(w0 * bf2f(a[k]) + w1 * bf2f(c[k]));
        *(s16x4*)&T[i][c4] = o;
    }
    __syncthreads();

    const short* Wp = Wg + 3 * 65536;
    f32x16 acc2[2];
    #pragma unroll
    for (int s = 0; s < 2; ++s)
        #pragma unroll
        for (int r = 0; r < 16; ++r) acc2[s][r] = 0.f;

    #pragma unroll 4
    for (int kk = 0; kk < 16; ++kk) {
        s16x8 a0 = *(const s16x8*)&T[ 0 + l31][kk*16 + h*8];
        s16x8 a1 = *(const s16x8*)&T[32 + l31][kk*16 + h*8];
        s16x8 bb = WFRAG(Wp, wid*32 + l31, kk*2 + h);
        acc2[0] = MFMA32(a0, bb, acc2[0]);
        acc2[1] = MFMA32(a1, bb, acc2[1]);
    }
    __syncthreads();

    float (*F)[256] = (float(*)[256])scr;          // 64n x 256o fp32
    {
        const int o = wid*32 + l31;
        #pragma unroll
        for (int nh = 0; nh < 2; ++nh) {
            #pragma unroll
            for (int r = 0; r < 16; ++r) {
                int n = nh*32 + (r & 3) + 8*(r >> 2) + 4*h;
                F[n][o ^ (n & 31)] = acc2[nh][r];
            }
        }
    }
    __syncthreads();

    const float* xb = xg + (size_t)b * Cc * Nn;
    float* ob = outg + (size_t)b * Cc * Nn;
    #pragma unroll 8
    for (int it = 0; it < 32; ++it) {
        int o = it*8 + wid;
        size_t idx = (size_t)o * Nn + i0 + lane;
        ob[idx] = xb[idx] + F[lane][o ^ (lane & 31)] + bp[o];
    }
}

// ---------------------------------------------------------------- launch
extern "C" void kernel_launch(void* const* d_in, const int* in_sizes, int n_in,
                              void* d_out, int out_size, void* d_ws, size_t ws_size,
                              hipStream_t stream)
{
    const float* x  = (const float*)d_in[0];
    const float* wq = (const float*)d_in[1];
    const float* bq = (const float*)d_in[2];
    const float* wk = (const float*)d_in[3];
    const float* bk = (const float*)d_in[4];
    const float* wv = (const float*)d_in[5];
    const float* bv = (const float*)d_in[6];
    const float* wp = (const float*)d_in[7];
    const float* bp = (const float*)d_in[8];

    const size_t elems  = (size_t)4 * Nn * Cc;          // shorts per K/V buffer
    const size_t wel    = 4 * 65536;                    // W8 shorts
    const size_t oel    = (size_t)256 * 32768;          // Opart shorts (16.8 MB)
    const size_t need   = (2*elems + wel + oel) * sizeof(short)
                        + (size_t)256 * 128 * sizeof(float);   // ~34.2 MiB (= r13, fits)
    if (ws_size < need) return;
    short* KT    = (short*)d_ws;               // [b][n][c] bf16
    short* V     = KT + elems;                 // [b] chunked V8[j>>3][c][j&7]
    short* Wbf   = V + elems;                  // 4 x chunked W8[c>>3][o][c&7]
    short* Opart = Wbf + wel;                  // 256 x [128][256] bf16
    float* Lw    = (float*)(Opart + oel);      // 256 x [128] fp32
    (void)in_sizes; (void)n_in; (void)out_size;

    wcvt_kernel<<<dim3(32, 4), 256, 0, stream>>>(wq, wk, wv, wp, Wbf);
    qkv_kernel<<<dim3(64, 4, 2), 256, 0, stream>>>(x, Wbf, bk, bv, KT, V);
    attn_kernel<<<dim3(256), 512, 0, stream>>>(KT, V, Wbf, bq, x, Opart, Lw);
    proj_kernel<<<dim3(64, 4), 512, 0, stream>>>(Opart, Lw, Wbf, bp, x, (float*)d_out);
}

// Round 11
// 202.773 us; speedup vs baseline: 1.2015x; 1.0982x over previous
//
#include <hip/hip_runtime.h>
#include <hip/hip_bf16.h>

// NonLocalBlock B=4,C=256,H=W=64 (N=4096) — round 15 (= r12, session best).
//  r13 (split-K 2 blocks/CU) and r14 (128-row fat windows) both REVERTED:
//  r13 showed co-resident blocks contend (157us at half work); r14 showed
//  window cost is work-proportional (4.15us/window at 2x work). The r12
//  configuration is the measured optimum of this decomposition:
//   - chunked V8/W8 global layouts (coalesced MFMA fragment loads)  [r6]
//   - proj fused into attn epilogue w/ swizzled-LDS coalesced store [r8]
//   - Q computed in attn prologue (no QT traffic)                   [r10]
//   - consumer raw s_barrier (V reg-dbuf spans barrier)             [r12]
// ws = KT | V8 | W8 = 17.3 MiB.

typedef __attribute__((ext_vector_type(4))) short s16x4;
typedef __attribute__((ext_vector_type(8))) short s16x8;
typedef __attribute__((ext_vector_type(16))) float f32x16;

#define MFMA32(a, b, c) __builtin_amdgcn_mfma_f32_32x32x16_bf16((a), (b), (c), 0, 0, 0)

constexpr int Cc = 256;
constexpr int Nn = 4096;

__device__ inline short f2bf(float f) {
    unsigned int u = __builtin_bit_cast(unsigned int, f);
    u = (u + 0x7fffu + ((u >> 16) & 1u)) >> 16;   // RNE
    return (short)u;
}

__device__ inline void gl_lds16(const short* g, short* l) {
    // async global->LDS, 16 B/lane; LDS dest = wave-uniform base + lane*16
    __builtin_amdgcn_global_load_lds((const unsigned int*)g, (unsigned int*)l, 16, 0, 0);
}

// 32x32x16 bf16 MFMA layouts (m74/m101-verified C/D; A/B symmetric k-map):
//   A[m=lane&31][k=(lane>>5)*8+j]   B[k=(lane>>5)*8+j][n=lane&31]
//   C/D: col=lane&31, row=(r&3)+8*(r>>2)+4*(lane>>5)

// W8 chunked fragment: row in [0,256), kc = chunk index (8 k elems each)
#define WFRAG(Wm, row, kc) (*(const s16x8*)&(Wm)[(size_t)(kc)*2048 + (size_t)(row)*8])

// ---------------------------------------------------------------- wcvt
// fp32 [o][c] -> bf16 chunked W8[c>>3][o][c&7]
__global__ __launch_bounds__(256, 4) void wcvt_kernel(
    const float* __restrict__ wq, const float* __restrict__ wk,
    const float* __restrict__ wv, const float* __restrict__ wp,
    short* __restrict__ W)
{
    const int m = blockIdx.y;
    const float* src = (m == 0) ? wq : (m == 1) ? wk : (m == 2) ? wv : wp;
    const int idx = (blockIdx.x * 256 + threadIdx.x) * 8;
    const int o = idx >> 8, c0 = idx & 255;
    float4 a = *(const float4*)(src + idx);
    float4 b = *(const float4*)(src + idx + 4);
    s16x8 p = { f2bf(a.x), f2bf(a.y), f2bf(a.z), f2bf(a.w),
                f2bf(b.x), f2bf(b.y), f2bf(b.z), f2bf(b.w) };
    *(s16x8*)(W + m * 65536 + ((size_t)(c0 >> 3) * 256 + o) * 8) = p;
}

// ---------------------------------------------------------------- qkv (K,V only)
// grid (64 n-tiles, 4 b, 2 mat), 256 thr. LDS xT tile 33.8 KB -> 4 blocks/CU.
__global__ __launch_bounds__(256, 4) void qkv_kernel(
    const float* __restrict__ x, const short* __restrict__ W,
    const float* __restrict__ bk, const float* __restrict__ bv,
    short* __restrict__ KT, short* __restrict__ V)
{
    const int nt = blockIdx.x, b = blockIdx.y, mat = blockIdx.z;  // 0=K 1=V
    const int n0 = nt * 64;
    const short* Wm = W + (mat + 1) * 65536;       // Wk at slot 1, Wv at slot 2
    const float* bias = (mat == 0) ? bk : bv;
    const int t = threadIdx.x, lane = t & 63, wid = t >> 6, h = lane >> 5, l31 = lane & 31;

    __shared__ alignas(16) short xT[64][264];      // x^T tile [n][c] bf16

    const float* xb = x + (size_t)b * Cc * Nn;
    #pragma unroll
    for (int r = 0; r < 16; ++r) {                 // transpose+cvt 64n x 256c
        int g = r * 256 + t;
        int n = g & 63, cg = g >> 6;
        float f0 = xb[(size_t)(4*cg + 0) * Nn + n0 + n];
        float f1 = xb[(size_t)(4*cg + 1) * Nn + n0 + n];
        float f2 = xb[(size_t)(4*cg + 2) * Nn + n0 + n];
        float f3 = xb[(size_t)(4*cg + 3) * Nn + n0 + n];
        s16x4 p = { f2bf(f0), f2bf(f1), f2bf(f2), f2bf(f3) };
        *(s16x4*)&xT[n][4*cg] = p;
    }
    __syncthreads();

    f32x16 acc[4];
    #pragma unroll
    for (int s = 0; s < 4; ++s)
        #pragma unroll
        for (int r = 0; r < 16; ++r) acc[s][r] = 0.f;

    if (mat == 0) {
        // K: D[n][o] = sum_c xT[n][c] w[o][c]   (A = xT LDS, B = W8 chunked)
        const int mw = wid & 1, nwb = (wid >> 1) * 4;
        #pragma unroll 4
        for (int kk = 0; kk < 16; ++kk) {
            s16x8 a = *(const s16x8*)&xT[mw*32 + l31][kk*16 + h*8];
            #pragma unroll
            for (int s = 0; s < 4; ++s) {
                s16x8 bb = WFRAG(Wm, (nwb + s)*32 + l31, kk*2 + h);
                acc[s] = MFMA32(a, bb, acc[s]);
            }
        }
        short* dst = KT + (size_t)b * Nn * Cc;     // row layout [n][c] for gl_lds
        #pragma unroll
        for (int s = 0; s < 4; ++s) {
            int o = (nwb + s)*32 + l31;
            float bia = bias[o];
            #pragma unroll
            for (int r = 0; r < 16; ++r) {
                int n = mw*32 + (r & 3) + 8*(r >> 2) + 4*h;
                dst[(size_t)(n0 + n) * Cc + o] = f2bf(acc[s][r] + bia);
            }
        }
    } else {
        // V: D[o][n] = sum_c w[o][c] xT[n][c]   (A = W8 chunked, B = xT LDS)
        #pragma unroll 4
        for (int kk = 0; kk < 16; ++kk) {
            s16x8 a0 = WFRAG(Wm, (wid*2 + 0)*32 + l31, kk*2 + h);
            s16x8 a1 = WFRAG(Wm, (wid*2 + 1)*32 + l31, kk*2 + h);
            s16x8 b0 = *(const s16x8*)&xT[ 0 + l31][kk*16 + h*8];
            s16x8 b1 = *(const s16x8*)&xT[32 + l31][kk*16 + h*8];
            acc[0] = MFMA32(a0, b0, acc[0]);
            acc[1] = MFMA32(a0, b1, acc[1]);
            acc[2] = MFMA32(a1, b0, acc[2]);
            acc[3] = MFMA32(a1, b1, acc[3]);
        }
        // V8[j>>3][c][j&7] chunked store
        short* dst = V + (size_t)b * Cc * Nn;
        #pragma unroll
        for (int sub = 0; sub < 4; ++sub) {
            int mc = sub >> 1, nc = sub & 1;
            int j = n0 + nc*32 + l31;
            #pragma unroll
            for (int r = 0; r < 16; ++r) {
                int o = (wid*2 + mc)*32 + (r & 3) + 8*(r >> 2) + 4*h;
                dst[((size_t)(j >> 3) * 256 + o) * 8 + (j & 7)] = f2bf(acc[sub][r] + bias[o]);
            }
        }
    }
}

// ---------------------------------------------------------------- attn (+Q, +proj fused)
// 512 thr: prologue computes the block's 64 Q-rows in-kernel; waves 0-3
// produce P (QK+exp, K via global_load_lds dbuf), waves 4-7 consume (PV,
// reg-dbuf V, RAW s_barrier — no vmcnt drain); fused proj epilogue.
__global__ __launch_bounds__(512, 2) void attn_kernel(
    const short* __restrict__ KTg, const short* __restrict__ Vg,
    const short* __restrict__ Wg, const float* __restrict__ bq,
    const float* __restrict__ bp, const float* __restrict__ xg,
    float* __restrict__ outg)
{
    const int bid = blockIdx.x;
    const int b  = (bid & 7) >> 1;              // batch per XCD pair
    const int qt = ((bid >> 3) << 1) | (bid & 1);
    const int i0 = qt * 64;

    const int t = threadIdx.x, lane = t & 63, wid = t >> 6, h = lane >> 5, l31 = lane & 31;

    __shared__ alignas(16) short Ks[2][64][256]; // swizzled: slot g holds granule g^(row&31)
    __shared__ alignas(16) short Ps[2][64][72];
    __shared__ float lpart[2][64];
    __shared__ float linv[64];
    short* KsF = &Ks[0][0][0];

    const short* Kb = KTg + (size_t)b * Nn * Cc;  // row layout [j][c]
    const short* Vb = Vg  + (size_t)b * Cc * Nn;  // chunked V8[j>>3][c][j&7]
    const float* xb = xg + (size_t)b * Cc * Nn;

    const float SC = 0.09016844005f;            // C^-0.5 * log2(e)
    f32x16 oacc[4];

    // ---------------- prologue: compute Q[i0..i0+63][256] in-kernel
    // xT tile over Ks[0], 16B-granule XOR swizzle: g16' = g16 ^ (row&15)
    {
        short* xTp = KsF;                        // [64] rows x 512 B
        #pragma unroll
        for (int r = 0; r < 8; ++r) {            // transpose+cvt 64n x 256c
            int g = r * 512 + t;
            int n = g & 63, cg = g >> 6;         // c = 4*cg
            float f0 = xb[(size_t)(4*cg + 0) * Nn + i0 + n];
            float f1 = xb[(size_t)(4*cg + 1) * Nn + i0 + n];
            float f2 = xb[(size_t)(4*cg + 2) * Nn + i0 + n];
            float f3 = xb[(size_t)(4*cg + 3) * Nn + i0 + n];
            s16x4 p = { f2bf(f0), f2bf(f1), f2bf(f2), f2bf(f3) };
            int bcol = (((cg >> 1) ^ (n & 15)) << 4) + (cg & 1) * 8;
            *(s16x4*)((char*)xTp + n * 512 + bcol) = p;
        }
        __syncthreads();

        // Q-GEMM: D[n 0..63][o = wid*32+l31] = sum_c xT[n][c] Wq[o][c]
        const short* Wq = Wg;                    // mat 0 chunked
        f32x16 qa[2];
        #pragma unroll
        for (int s = 0; s < 2; ++s)
            #pragma unroll
            for (int r = 0; r < 16; ++r) qa[s][r] = 0.f;
        #pragma unroll 4
        for (int kk = 0; kk < 16; ++kk) {
            int gsw = ((kk*2 + h) ^ (l31 & 15)) << 4;
            s16x8 a0 = *(const s16x8*)((char*)xTp + ( 0 + l31) * 512 + gsw);
            s16x8 a1 = *(const s16x8*)((char*)xTp + (32 + l31) * 512 + gsw);
            s16x8 bb = WFRAG(Wq, wid*32 + l31, kk*2 + h);
            qa[0] = MFMA32(a0, bb, qa[0]);
            qa[1] = MFMA32(a1, bb, qa[1]);
        }
        // D + bq -> Fq (over Ks[1]), bf16, same granule swizzle
        short* Fq = KsF + 16384;
        const int o = wid*32 + l31;
        const float bo = bq[o];
        #pragma unroll
        for (int mw2 = 0; mw2 < 2; ++mw2)
            #pragma unroll
            for (int r = 0; r < 16; ++r) {
                int n = mw2*32 + (r & 3) + 8*(r >> 2) + 4*h;
                int bcol = (((o >> 3) ^ (n & 15)) << 4) + (o & 7) * 2;
                *(short*)((char*)Fq + n * 512 + bcol) = f2bf(qa[mw2][r] + bo);
            }
    }
    __syncthreads();

    if (wid < 4) {
        // ---------------- producer: S^T = K Q^T, exp, P
        const int w4 = wid, mj = w4 >> 1, ni = w4 & 1;

        s16x8 qf[16];                            // from Fq (Ks[1] area)
        {
            const short* Fq = KsF + 16384;
            const int qrow = ni*32 + l31;
            #pragma unroll
            for (int kc = 0; kc < 16; ++kc) {
                int bcol = ((kc*2 + h) ^ (qrow & 15)) << 4;
                qf[kc] = *(const s16x8*)((char*)Fq + qrow * 512 + bcol);
            }
        }
        float lacc = 0.f;
        const int rl = mj*32 + l31;             // A-frag row; (rl&31)==l31

        for (int tt = 0; tt < 66; ++tt) {
            if (tt < 64) {                       // stage K tile tt (async DMA)
                const int kb = tt & 1;
                #pragma unroll
                for (int it = 0; it < 8; ++it) {
                    int r = (w4*8 + it)*2 + (lane >> 5);
                    int g = l31 ^ (r & 31);
                    const short* gp = Kb + (size_t)(tt*64 + r) * Cc + g*8;
                    short* lp = KsF + kb*16384 + (w4*8 + it)*512;  // wave-uniform
                    gl_lds16(gp, lp);
                }
            }
            if (tt >= 1 && tt < 65) {
                const int jt = tt - 1, kb = jt & 1;
                const short* abase = KsF + kb*16384 + rl*256;
                f32x16 s0, s1;
                #pragma unroll
                for (int r = 0; r < 16; ++r) { s0[r] = 0.f; s1[r] = 0.f; }
                #pragma unroll
                for (int kc = 0; kc < 8; ++kc) {
                    s16x8 a0 = *(const s16x8*)(abase + (((kc*4 + 0 + h) ^ l31) << 3));
                    s16x8 a1 = *(const s16x8*)(abase + (((kc*4 + 2 + h) ^ l31) << 3));
                    s0 = MFMA32(a0, qf[2*kc + 0], s0);
                    s1 = MFMA32(a1, qf[2*kc + 1], s1);
                }
                float ps[16], lsum = 0.f;
                #pragma unroll
                for (int r = 0; r < 16; ++r) {
                    float e = exp2f((s0[r] + s1[r]) * SC);
                    ps[r] = e; lsum += e;
                }
                lsum += __shfl_xor(lsum, 32);
                lacc += lsum;
                const int ip = ni*32 + l31;
                #pragma unroll
                for (int g = 0; g < 4; ++g) {
                    s16x4 pk = { f2bf(ps[4*g+0]), f2bf(ps[4*g+1]),
                                 f2bf(ps[4*g+2]), f2bf(ps[4*g+3]) };
                    *(s16x4*)&Ps[kb][ip][mj*32 + g*8 + 4*h] = pk;
                }
            }
            __syncthreads();                     // producer: full drain (Ks + Ps publish)
        }
        if (h == 0) lpart[mj][ni*32 + l31] = lacc;
    } else {
        // ---------------- consumer: O^T[c][i] += V[c][j] P[i][j]
        const int w2 = wid - 4;
        #pragma unroll
        for (int s = 0; s < 4; ++s)
            #pragma unroll
            for (int r = 0; r < 16; ++r) oacc[s][r] = 0.f;

        s16x8 vA[8], vB[8];
        // chunked V8: element (c,j) at ((j>>3)*256 + c)*8 + (j&7)
        const short* vc0 = Vb + (size_t)(w2*64 +  0 + l31) * 8 + h*2048;
        const short* vc1 = Vb + (size_t)(w2*64 + 32 + l31) * 8 + h*2048;

        for (int tp = 0; tp < 33; ++tp) {
            const int t0 = tp*2, t1 = t0 + 1;
            // even step t0: issue tile t0-1 -> vA ; consume tile t0-2 from vB
            if (t0 >= 1 && t0 <= 64) {
                const size_t jc = (size_t)(t0 - 1) * 8;   // j0>>3
                #pragma unroll
                for (int kj = 0; kj < 4; ++kj) {
                    vA[kj]   = *(const s16x8*)(vc0 + (jc + kj*2) * 2048);
                    vA[4+kj] = *(const s16x8*)(vc1 + (jc + kj*2) * 2048);
                }
            }
            if (t0 >= 2) {
                const int pb = (t0 - 2) & 1;
                s16x8 p0[4], p1[4];
                #pragma unroll
                for (int kj = 0; kj < 4; ++kj) {
                    p0[kj] = *(const s16x8*)&Ps[pb][ 0 + l31][kj*16 + h*8];
                    p1[kj] = *(const s16x8*)&Ps[pb][32 + l31][kj*16 + h*8];
                }
                #pragma unroll
                for (int kj = 0; kj < 4; ++kj) {
                    oacc[0] = MFMA32(vB[kj],   p0[kj], oacc[0]);
                    oacc[1] = MFMA32(vB[kj],   p1[kj], oacc[1]);
                    oacc[2] = MFMA32(vB[4+kj], p0[kj], oacc[2]);
                    oacc[3] = MFMA32(vB[4+kj], p1[kj], oacc[3]);
                }
            }
            // raw barrier: keep this window's V loads in flight (compiler
            // inserts the counted vmcnt at next window's first use of vA/vB)
            asm volatile("s_barrier" ::: "memory");
            // odd step t1: issue tile t1-1 -> vB ; consume tile t1-2 from vA
            if (t1 <= 64) {
                const size_t jc = (size_t)(t1 - 1) * 8;
                #pragma unroll
                for (int kj = 0; kj < 4; ++kj) {
                    vB[kj]   = *(const s16x8*)(vc0 + (jc + kj*2) * 2048);
                    vB[4+kj] = *(const s16x8*)(vc1 + (jc + kj*2) * 2048);
                }
            }
            if (t1 >= 2) {
                const int pb = (t1 - 2) & 1;
                s16x8 p0[4], p1[4];
                #pragma unroll
                for (int kj = 0; kj < 4; ++kj) {
                    p0[kj] = *(const s16x8*)&Ps[pb][ 0 + l31][kj*16 + h*8];
                    p1[kj] = *(const s16x8*)&Ps[pb][32 + l31][kj*16 + h*8];
                }
                #pragma unroll
                for (int kj = 0; kj < 4; ++kj) {
                    oacc[0] = MFMA32(vA[kj],   p0[kj], oacc[0]);
                    oacc[1] = MFMA32(vA[kj],   p1[kj], oacc[1]);
                    oacc[2] = MFMA32(vA[4+kj], p0[kj], oacc[2]);
                    oacc[3] = MFMA32(vA[4+kj], p1[kj], oacc[3]);
                }
            }
            asm volatile("s_barrier" ::: "memory");
        }
    }

    // ---------------- epilogue A: normalize, LDS-transpose O -> T[n][c]
    __syncthreads();
    if (t < 64) linv[t] = 1.0f / (lpart[0][t] + lpart[1][t]);
    __syncthreads();
    short (*T)[264] = (short(*)[264])KsF;       // scratch over Ks
    if (wid >= 4) {
        const int w2 = wid - 4;
        #pragma unroll
        for (int sub = 0; sub < 4; ++sub) {
            int mc = sub >> 1, nc = sub & 1;
            int ip = nc*32 + l31;
            float rl2 = linv[ip];
            #pragma unroll
            for (int r = 0; r < 16; ++r) {
                int c = w2*64 + mc*32 + (r & 3) + 8*(r >> 2) + 4*h;
                T[ip][c] = f2bf(oacc[sub][r] * rl2);
            }
        }
    }
    __syncthreads();

    // ---------------- epilogue B: fused proj. D[n][o] = sum_c T[n][c] Wp[o][c]
    {
        const short* Wp = Wg + 3 * 65536;
        f32x16 acc2[2];
        #pragma unroll
        for (int s = 0; s < 2; ++s)
            #pragma unroll
            for (int r = 0; r < 16; ++r) acc2[s][r] = 0.f;

        #pragma unroll 4
        for (int kk = 0; kk < 16; ++kk) {
            s16x8 a0 = *(const s16x8*)&T[ 0 + l31][kk*16 + h*8];
            s16x8 a1 = *(const s16x8*)&T[32 + l31][kk*16 + h*8];
            s16x8 bb = WFRAG(Wp, wid*32 + l31, kk*2 + h);
            acc2[0] = MFMA32(a0, bb, acc2[0]);
            acc2[1] = MFMA32(a1, bb, acc2[1]);
        }
        __syncthreads();                         // all waves done reading T

        // bounce acc2 through XOR-swizzled fp32 tile F[n][o^(n&31)]
        float (*F)[256] = (float(*)[256])KsF;    // 64n x 256o fp32 = 64 KB
        {
            const int o = wid*32 + l31;
            #pragma unroll
            for (int nh = 0; nh < 2; ++nh) {
                #pragma unroll
                for (int r = 0; r < 16; ++r) {
                    int n = nh*32 + (r & 3) + 8*(r >> 2) + 4*h;
                    F[n][o ^ (n & 31)] = acc2[nh][r];
                }
            }
        }
        __syncthreads();

        // coalesced residual+store: lanes take consecutive n, fixed o
        float* ob = outg + (size_t)b * Cc * Nn;
        #pragma unroll 8
        for (int it = 0; it < 32; ++it) {
            int o = it*8 + wid;
            size_t idx = (size_t)o * Nn + i0 + lane;
            ob[idx] = xb[idx] + F[lane][o ^ (lane & 31)] + bp[o];
        }
    }
}

// ---------------------------------------------------------------- launch
extern "C" void kernel_launch(void* const* d_in, const int* in_sizes, int n_in,
                              void* d_out, int out_size, void* d_ws, size_t ws_size,
                              hipStream_t stream)
{
    const float* x  = (const float*)d_in[0];
    const float* wq = (const float*)d_in[1];
    const float* bq = (const float*)d_in[2];
    const float* wk = (const float*)d_in[3];
    const float* bk = (const float*)d_in[4];
    const float* wv = (const float*)d_in[5];
    const float* bv = (const float*)d_in[6];
    const float* wp = (const float*)d_in[7];
    const float* bp = (const float*)d_in[8];

    const size_t elems = (size_t)4 * Nn * Cc;                 // 4.19 M / buffer
    const size_t need  = (2 * elems + 4 * 65536) * sizeof(short);  // 17.3 MiB
    if (ws_size < need) return;
    short* KT  = (short*)d_ws;                 // [b][n][c] bf16
    short* V   = KT + elems;                   // [b] chunked V8[j>>3][c][j&7]
    short* Wbf = V + elems;                    // 4 x chunked W8[c>>3][o][c&7]
    (void)in_sizes; (void)n_in; (void)out_size;

    wcvt_kernel<<<dim3(32, 4), 256, 0, stream>>>(wq, wk, wv, wp, Wbf);
    qkv_kernel<<<dim3(64, 4, 2), 256, 0, stream>>>(x, Wbf, bk, bv, KT, V);
    attn_kernel<<<dim3(256), 512, 0, stream>>>(KT, V, Wbf, bq, bp, x, (float*)d_out);
}

// Round 12
// 188.729 us; speedup vs baseline: 1.2909x; 1.0744x over previous
//
#include <hip/hip_runtime.h>
#include <hip/hip_bf16.h>

// NonLocalBlock B=4,C=256,H=W=64 (N=4096) — round 16.
//  Mechanism: fp8 e4m3 (OCP, native gfx950) for K, V, Q, P. MFMA count and
//  shape unchanged (32x32x16 fp8 = same tiling as bf16); all GEMM inputs
//  that feed accuracy-critical paths (x, weights, O, proj) stay bf16/fp32.
//  Halves: K staging bytes (8->4 gl_lds/window), K frag ds_reads (b64),
//  V reg loads (8B), Ps LDS traffic, qkv K/V store bytes, qf/vA/vB VGPRs.
//  Pipeline/barrier structure = r12/r15 (session best) byte-for-byte.
//  LDS 85 -> 66.5 KB. ws = K8 | V8 | W8 = 8.5 MiB.

typedef __attribute__((ext_vector_type(4))) short s16x4;
typedef __attribute__((ext_vector_type(8))) short s16x8;
typedef __attribute__((ext_vector_type(16))) float f32x16;

#define MFMA32(a, b, c)   __builtin_amdgcn_mfma_f32_32x32x16_bf16((a), (b), (c), 0, 0, 0)
#define MFMA32F8(a, b, c) __builtin_amdgcn_mfma_f32_32x32x16_fp8_fp8((a), (b), (c), 0, 0, 0)

constexpr int Cc = 256;
constexpr int Nn = 4096;

__device__ inline short f2bf(float f) {
    unsigned int u = __builtin_bit_cast(unsigned int, f);
    u = (u + 0x7fffu + ((u >> 16) & 1u)) >> 16;   // RNE
    return (short)u;
}
__device__ inline unsigned char f2fp8(float f) {   // f32 -> OCP e4m3, RNE-sat
    return (unsigned char)(__builtin_amdgcn_cvt_pk_fp8_f32(f, f, 0, false) & 0xff);
}

__device__ inline void gl_lds16(const void* g, void* l) {
    // async global->LDS, 16 B/lane; LDS dest = wave-uniform base + lane*16
    __builtin_amdgcn_global_load_lds((const unsigned int*)g, (unsigned int*)l, 16, 0, 0);
}

// 32x32x16 MFMA layouts (bf16 verified m74/m101; fp8 same maps, 8B frags):
//   A[m=lane&31][k=(lane>>5)*8+j]   B[k=(lane>>5)*8+j][n=lane&31]
//   C/D: col=lane&31, row=(r&3)+8*(r>>2)+4*(lane>>5)

// W8 chunked fragment: row in [0,256), kc = chunk index (8 k elems each)
#define WFRAG(Wm, row, kc) (*(const s16x8*)&(Wm)[(size_t)(kc)*2048 + (size_t)(row)*8])

// ---------------------------------------------------------------- wcvt
// fp32 [o][c] -> bf16 chunked W8[c>>3][o][c&7]  (weights stay bf16)
__global__ __launch_bounds__(256, 4) void wcvt_kernel(
    const float* __restrict__ wq, const float* __restrict__ wk,
    const float* __restrict__ wv, const float* __restrict__ wp,
    short* __restrict__ W)
{
    const int m = blockIdx.y;
    const float* src = (m == 0) ? wq : (m == 1) ? wk : (m == 2) ? wv : wp;
    const int idx = (blockIdx.x * 256 + threadIdx.x) * 8;
    const int o = idx >> 8, c0 = idx & 255;
    float4 a = *(const float4*)(src + idx);
    float4 b = *(const float4*)(src + idx + 4);
    s16x8 p = { f2bf(a.x), f2bf(a.y), f2bf(a.z), f2bf(a.w),
                f2bf(b.x), f2bf(b.y), f2bf(b.z), f2bf(b.w) };
    *(s16x8*)(W + m * 65536 + ((size_t)(c0 >> 3) * 256 + o) * 8) = p;
}

// ---------------------------------------------------------------- qkv (K,V only)
// grid (64 n-tiles, 4 b, 2 mat), 256 thr. GEMMs bf16; outputs quantized fp8.
// K8: row-major [n][c] fp8 (1B).  V8: chunked [j>>3][c][j&7] fp8.
__global__ __launch_bounds__(256, 4) void qkv_kernel(
    const float* __restrict__ x, const short* __restrict__ W,
    const float* __restrict__ bk, const float* __restrict__ bv,
    unsigned char* __restrict__ KT, unsigned char* __restrict__ V)
{
    const int nt = blockIdx.x, b = blockIdx.y, mat = blockIdx.z;  // 0=K 1=V
    const int n0 = nt * 64;
    const short* Wm = W + (mat + 1) * 65536;       // Wk slot 1, Wv slot 2
    const float* bias = (mat == 0) ? bk : bv;
    const int t = threadIdx.x, lane = t & 63, wid = t >> 6, h = lane >> 5, l31 = lane & 31;

    __shared__ alignas(16) short xT[64][264];      // x^T tile [n][c] bf16

    const float* xb = x + (size_t)b * Cc * Nn;
    #pragma unroll
    for (int r = 0; r < 16; ++r) {                 // transpose+cvt 64n x 256c
        int g = r * 256 + t;
        int n = g & 63, cg = g >> 6;
        float f0 = xb[(size_t)(4*cg + 0) * Nn + n0 + n];
        float f1 = xb[(size_t)(4*cg + 1) * Nn + n0 + n];
        float f2 = xb[(size_t)(4*cg + 2) * Nn + n0 + n];
        float f3 = xb[(size_t)(4*cg + 3) * Nn + n0 + n];
        s16x4 p = { f2bf(f0), f2bf(f1), f2bf(f2), f2bf(f3) };
        *(s16x4*)&xT[n][4*cg] = p;
    }
    __syncthreads();

    f32x16 acc[4];
    #pragma unroll
    for (int s = 0; s < 4; ++s)
        #pragma unroll
        for (int r = 0; r < 16; ++r) acc[s][r] = 0.f;

    if (mat == 0) {
        // K: D[n][o] = sum_c xT[n][c] w[o][c]
        const int mw = wid & 1, nwb = (wid >> 1) * 4;
        #pragma unroll 4
        for (int kk = 0; kk < 16; ++kk) {
            s16x8 a = *(const s16x8*)&xT[mw*32 + l31][kk*16 + h*8];
            #pragma unroll
            for (int s = 0; s < 4; ++s) {
                s16x8 bb = WFRAG(Wm, (nwb + s)*32 + l31, kk*2 + h);
                acc[s] = MFMA32(a, bb, acc[s]);
            }
        }
        unsigned char* dst = KT + (size_t)b * Nn * Cc;   // fp8 [n][c]
        #pragma unroll
        for (int s = 0; s < 4; ++s) {
            int o = (nwb + s)*32 + l31;
            float bia = bias[o];
            #pragma unroll
            for (int r = 0; r < 16; ++r) {
                int n = mw*32 + (r & 3) + 8*(r >> 2) + 4*h;
                dst[(size_t)(n0 + n) * Cc + o] = f2fp8(acc[s][r] + bia);
            }
        }
    } else {
        // V: D[o][n] = sum_c w[o][c] xT[n][c]
        #pragma unroll 4
        for (int kk = 0; kk < 16; ++kk) {
            s16x8 a0 = WFRAG(Wm, (wid*2 + 0)*32 + l31, kk*2 + h);
            s16x8 a1 = WFRAG(Wm, (wid*2 + 1)*32 + l31, kk*2 + h);
            s16x8 b0 = *(const s16x8*)&xT[ 0 + l31][kk*16 + h*8];
            s16x8 b1 = *(const s16x8*)&xT[32 + l31][kk*16 + h*8];
            acc[0] = MFMA32(a0, b0, acc[0]);
            acc[1] = MFMA32(a0, b1, acc[1]);
            acc[2] = MFMA32(a1, b0, acc[2]);
            acc[3] = MFMA32(a1, b1, acc[3]);
        }
        unsigned char* dst = V + (size_t)b * Cc * Nn;    // fp8 chunked V8
        #pragma unroll
        for (int sub = 0; sub < 4; ++sub) {
            int mc = sub >> 1, nc = sub & 1;
            int j = n0 + nc*32 + l31;
            #pragma unroll
            for (int r = 0; r < 16; ++r) {
                int o = (wid*2 + mc)*32 + (r & 3) + 8*(r >> 2) + 4*h;
                dst[(((size_t)(j >> 3) * 256 + o) << 3) + (j & 7)] = f2fp8(acc[sub][r] + bias[o]);
            }
        }
    }
}

// ---------------------------------------------------------------- attn (+Q, +proj fused; fp8 core)
// Structure = r12/r15 exactly. fp8 deltas: Ks [2][64][256]B (16B-granule XOR
// swz g^(r&15)); Fq [64][256]B separate region (never overwritten); Ps
// [2][64][72]B (72B pad -> 2-way free); frags are 8B `long`; 4 gl_lds/wave.
// LDS map: [0,32768) Ks (xTp/T/F overlay) | [32768,49152) Fq | [49152,58368)
// Ps | [65536,66048) lpart | [66048,66304) linv.  F fp32 overlays [0,65536).
__global__ __launch_bounds__(512, 2) void attn_kernel(
    const unsigned char* __restrict__ KTg, const unsigned char* __restrict__ Vg,
    const short* __restrict__ Wg, const float* __restrict__ bq,
    const float* __restrict__ bp, const float* __restrict__ xg,
    float* __restrict__ outg)
{
    const int bid = blockIdx.x;
    const int b  = (bid & 7) >> 1;              // batch per XCD pair
    const int qt = ((bid >> 3) << 1) | (bid & 1);
    const int i0 = qt * 64;

    const int t = threadIdx.x, lane = t & 63, wid = t >> 6, h = lane >> 5, l31 = lane & 31;

    __shared__ alignas(16) char LDS[66304];
    char* KsB = LDS;                            // [2][64][256] fp8 K staging
    unsigned char* FqB = (unsigned char*)(LDS + 32768);  // [64][256] fp8 Q
    char* PsB = LDS + 49152;                    // [2][64][72] fp8 P
    float* lpart = (float*)(LDS + 65536);       // [2][64]
    float* linv  = (float*)(LDS + 66048);       // [64]

    const unsigned char* Kb = KTg + (size_t)b * Nn * Cc;  // fp8 [j][c]
    const unsigned char* Vb = Vg  + (size_t)b * Cc * Nn;  // fp8 chunked V8
    const float* xb = xg + (size_t)b * Cc * Nn;

    const float SC = 0.09016844005f;            // C^-0.5 * log2(e)
    f32x16 oacc[4];

    // ---------------- prologue: Q[i0..i0+63][256] in-kernel (bf16 GEMM -> fp8 Fq)
    {
        short* xTp = (short*)LDS;                // 64 rows x 512 B bf16 (over Ks)
        #pragma unroll
        for (int r = 0; r < 8; ++r) {            // transpose+cvt 64n x 256c
            int g = r * 512 + t;
            int n = g & 63, cg = g >> 6;         // c = 4*cg
            float f0 = xb[(size_t)(4*cg + 0) * Nn + i0 + n];
            float f1 = xb[(size_t)(4*cg + 1) * Nn + i0 + n];
            float f2 = xb[(size_t)(4*cg + 2) * Nn + i0 + n];
            float f3 = xb[(size_t)(4*cg + 3) * Nn + i0 + n];
            s16x4 p = { f2bf(f0), f2bf(f1), f2bf(f2), f2bf(f3) };
            int bcol = (((cg >> 1) ^ (n & 15)) << 4) + (cg & 1) * 8;
            *(s16x4*)((char*)xTp + n * 512 + bcol) = p;
        }
        __syncthreads();

        const short* Wq = Wg;                    // mat 0 chunked bf16
        f32x16 qa[2];
        #pragma unroll
        for (int s = 0; s < 2; ++s)
            #pragma unroll
            for (int r = 0; r < 16; ++r) qa[s][r] = 0.f;
        #pragma unroll 4
        for (int kk = 0; kk < 16; ++kk) {
            int gsw = ((kk*2 + h) ^ (l31 & 15)) << 4;
            s16x8 a0 = *(const s16x8*)((char*)xTp + ( 0 + l31) * 512 + gsw);
            s16x8 a1 = *(const s16x8*)((char*)xTp + (32 + l31) * 512 + gsw);
            s16x8 bb = WFRAG(Wq, wid*32 + l31, kk*2 + h);
            qa[0] = MFMA32(a0, bb, qa[0]);
            qa[1] = MFMA32(a1, bb, qa[1]);
        }
        // D + bq -> Fq fp8 (separate region; 16B-granule XOR swizzle on o)
        const int o = wid*32 + l31;
        const float bo = bq[o];
        #pragma unroll
        for (int mw2 = 0; mw2 < 2; ++mw2)
            #pragma unroll
            for (int r = 0; r < 16; ++r) {
                int n = mw2*32 + (r & 3) + 8*(r >> 2) + 4*h;
                FqB[n*256 + (((o >> 4) ^ (n & 15)) << 4) + (o & 15)] = f2fp8(qa[mw2][r] + bo);
            }
    }
    __syncthreads();

    if (wid < 4) {
        // ---------------- producer: S^T = K Q^T (fp8 MFMA), exp, P fp8
        const int w4 = wid, mj = w4 >> 1, ni = w4 & 1;

        long qf[16];                             // 8B fp8 frags from Fq
        {
            const int qrow = ni*32 + l31;
            #pragma unroll
            for (int kc = 0; kc < 16; ++kc)
                qf[kc] = *(const long*)(FqB + qrow*256 + ((kc ^ (qrow & 15)) << 4) + h*8);
        }
        float lacc = 0.f;
        const int rl = mj*32 + l31;              // A-frag row (j)
        const int ip = ni*32 + l31;
        const int rsw = rl & 15;

        for (int tt = 0; tt < 66; ++tt) {
            if (tt < 64) {                       // stage K tile tt: 4 gl_lds/wave
                const int kb = tt & 1;
                #pragma unroll
                for (int it = 0; it < 4; ++it) {
                    int r = w4*16 + it*4 + (lane >> 4);
                    int g = (lane & 15) ^ (r & 15);
                    const unsigned char* gp = Kb + (size_t)(tt*64 + r) * Cc + g*16;
                    char* lp = KsB + kb*16384 + (w4*16 + it*4)*256;  // wave-uniform
                    gl_lds16(gp, lp);
                }
            }
            if (tt >= 1 && tt < 65) {
                const int jt = tt - 1, kb = jt & 1;
                const char* abase = KsB + kb*16384 + rl*256;
                f32x16 s0, s1;
                #pragma unroll
                for (int r = 0; r < 16; ++r) { s0[r] = 0.f; s1[r] = 0.f; }
                #pragma unroll
                for (int kc = 0; kc < 8; ++kc) {
                    long a0 = *(const long*)(abase + (((2*kc + 0) ^ rsw) << 4) + h*8);
                    long a1 = *(const long*)(abase + (((2*kc + 1) ^ rsw) << 4) + h*8);
                    s0 = MFMA32F8(a0, qf[2*kc + 0], s0);
                    s1 = MFMA32F8(a1, qf[2*kc + 1], s1);
                }
                float ps[16], lsum = 0.f;
                #pragma unroll
                for (int r = 0; r < 16; ++r) {
                    float e = exp2f((s0[r] + s1[r]) * SC);
                    ps[r] = e; lsum += e;
                }
                lsum += __shfl_xor(lsum, 32);
                lacc += lsum;
                char* pw = PsB + kb*4608 + ip*72 + mj*32 + 4*h;
                #pragma unroll
                for (int g = 0; g < 4; ++g) {    // pack 4 fp8 via 2 cvt_pk
                    int w = __builtin_amdgcn_cvt_pk_fp8_f32(ps[4*g+0], ps[4*g+1], 0, false);
                    w = __builtin_amdgcn_cvt_pk_fp8_f32(ps[4*g+2], ps[4*g+3], w, true);
                    *(int*)(pw + g*8) = w;
                }
            }
            __syncthreads();                     // producer: full drain (Ks + Ps publish)
        }
        if (h == 0) lpart[mj*64 + ip] = lacc;
    } else {
        // ---------------- consumer: O^T[c][i] += V[c][j] P[i][j] (fp8 MFMA)
        const int w2 = wid - 4;
        #pragma unroll
        for (int s = 0; s < 4; ++s)
            #pragma unroll
            for (int r = 0; r < 16; ++r) oacc[s][r] = 0.f;

        long vA[8], vB[8];
        // fp8 V8: element (c,j) at ((j>>3)*256 + c)*8 + (j&7)
        const unsigned char* vc0 = Vb + (size_t)(w2*64 +  0 + l31) * 8 + h*2048;
        const unsigned char* vc1 = Vb + (size_t)(w2*64 + 32 + l31) * 8 + h*2048;

        for (int tp = 0; tp < 33; ++tp) {
            const int t0 = tp*2, t1 = t0 + 1;
            // even step t0: issue tile t0-1 -> vA ; consume tile t0-2 from vB
            if (t0 >= 1 && t0 <= 64) {
                const size_t jc = (size_t)(t0 - 1) * 8;
                #pragma unroll
                for (int kj = 0; kj < 4; ++kj) {
                    vA[kj]   = *(const long*)(vc0 + (jc + kj*2) * 2048);
                    vA[4+kj] = *(const long*)(vc1 + (jc + kj*2) * 2048);
                }
            }
            if (t0 >= 2) {
                const int pb = (t0 - 2) & 1;
                const char* pr = PsB + pb*4608 + l31*72 + h*8;
                long p0[4], p1[4];
                #pragma unroll
                for (int kj = 0; kj < 4; ++kj) {
                    p0[kj] = *(const long*)(pr + kj*16);
                    p1[kj] = *(const long*)(pr + 2304 + kj*16);   // rows 32..63
                }
                #pragma unroll
                for (int kj = 0; kj < 4; ++kj) {
                    oacc[0] = MFMA32F8(vB[kj],   p0[kj], oacc[0]);
                    oacc[1] = MFMA32F8(vB[kj],   p1[kj], oacc[1]);
                    oacc[2] = MFMA32F8(vB[4+kj], p0[kj], oacc[2]);
                    oacc[3] = MFMA32F8(vB[4+kj], p1[kj], oacc[3]);
                }
            }
            asm volatile("s_barrier" ::: "memory");   // no drain: V stays in flight
            // odd step t1: issue tile t1-1 -> vB ; consume tile t1-2 from vA
            if (t1 <= 64) {
                const size_t jc = (size_t)(t1 - 1) * 8;
                #pragma unroll
                for (int kj = 0; kj < 4; ++kj) {
                    vB[kj]   = *(const long*)(vc0 + (jc + kj*2) * 2048);
                    vB[4+kj] = *(const long*)(vc1 + (jc + kj*2) * 2048);
                }
            }
            if (t1 >= 2) {
                const int pb = (t1 - 2) & 1;
                const char* pr = PsB + pb*4608 + l31*72 + h*8;
                long p0[4], p1[4];
                #pragma unroll
                for (int kj = 0; kj < 4; ++kj) {
                    p0[kj] = *(const long*)(pr + kj*16);
                    p1[kj] = *(const long*)(pr + 2304 + kj*16);
                }
                #pragma unroll
                for (int kj = 0; kj < 4; ++kj) {
                    oacc[0] = MFMA32F8(vA[kj],   p0[kj], oacc[0]);
                    oacc[1] = MFMA32F8(vA[kj],   p1[kj], oacc[1]);
                    oacc[2] = MFMA32F8(vA[4+kj], p0[kj], oacc[2]);
                    oacc[3] = MFMA32F8(vA[4+kj], p1[kj], oacc[3]);
                }
            }
            asm volatile("s_barrier" ::: "memory");
        }
    }

    // ---------------- epilogue A: normalize, LDS-transpose O -> T[n][c] (bf16)
    __syncthreads();
    if (t < 64) linv[t] = 1.0f / (lpart[t] + lpart[64 + t]);
    __syncthreads();
    short (*T)[264] = (short(*)[264])LDS;       // overlays Ks+Fq head (dead)
    if (wid >= 4) {
        const int w2 = wid - 4;
        #pragma unroll
        for (int sub = 0; sub < 4; ++sub) {
            int mc = sub >> 1, nc = sub & 1;
            int ip = nc*32 + l31;
            float rl2 = linv[ip];
            #pragma unroll
            for (int r = 0; r < 16; ++r) {
                int c = w2*64 + mc*32 + (r & 3) + 8*(r >> 2) + 4*h;
                T[ip][c] = f2bf(oacc[sub][r] * rl2);
            }
        }
    }
    __syncthreads();

    // ---------------- epilogue B: fused proj (bf16). D[n][o] = sum_c T[n][c] Wp[o][c]
    {
        const short* Wp = Wg + 3 * 65536;
        f32x16 acc2[2];
        #pragma unroll
        for (int s = 0; s < 2; ++s)
            #pragma unroll
            for (int r = 0; r < 16; ++r) acc2[s][r] = 0.f;

        #pragma unroll 4
        for (int kk = 0; kk < 16; ++kk) {
            s16x8 a0 = *(const s16x8*)&T[ 0 + l31][kk*16 + h*8];
            s16x8 a1 = *(const s16x8*)&T[32 + l31][kk*16 + h*8];
            s16x8 bb = WFRAG(Wp, wid*32 + l31, kk*2 + h);
            acc2[0] = MFMA32(a0, bb, acc2[0]);
            acc2[1] = MFMA32(a1, bb, acc2[1]);
        }
        __syncthreads();                         // all waves done reading T

        // bounce acc2 through XOR-swizzled fp32 tile F[n][o^(n&31)]
        float (*F)[256] = (float(*)[256])LDS;    // 64n x 256o fp32 = 64 KB
        {
            const int o = wid*32 + l31;
            #pragma unroll
            for (int nh = 0; nh < 2; ++nh) {
                #pragma unroll
                for (int r = 0; r < 16; ++r) {
                    int n = nh*32 + (r & 3) + 8*(r >> 2) + 4*h;
                    F[n][o ^ (n & 31)] = acc2[nh][r];
                }
            }
        }
        __syncthreads();

        // coalesced residual+store: lanes take consecutive n, fixed o
        float* ob = outg + (size_t)b * Cc * Nn;
        #pragma unroll 8
        for (int it = 0; it < 32; ++it) {
            int o = it*8 + wid;
            size_t idx = (size_t)o * Nn + i0 + lane;
            ob[idx] = xb[idx] + F[lane][o ^ (lane & 31)] + bp[o];
        }
    }
}

// ---------------------------------------------------------------- launch
extern "C" void kernel_launch(void* const* d_in, const int* in_sizes, int n_in,
                              void* d_out, int out_size, void* d_ws, size_t ws_size,
                              hipStream_t stream)
{
    const float* x  = (const float*)d_in[0];
    const float* wq = (const float*)d_in[1];
    const float* bq = (const float*)d_in[2];
    const float* wk = (const float*)d_in[3];
    const float* bk = (const float*)d_in[4];
    const float* wv = (const float*)d_in[5];
    const float* bv = (const float*)d_in[6];
    const float* wp = (const float*)d_in[7];
    const float* bp = (const float*)d_in[8];

    const size_t kvbytes = (size_t)4 * Nn * Cc;            // 4 MiB per fp8 buffer
    const size_t wel     = (size_t)4 * 65536;              // W8 shorts
    const size_t need    = 2 * kvbytes + wel * sizeof(short);   // ~8.5 MiB
    if (ws_size < need) return;
    unsigned char* KT = (unsigned char*)d_ws;   // [b][n][c] fp8
    unsigned char* V  = KT + kvbytes;           // [b] chunked V8 fp8
    short* Wbf = (short*)(V + kvbytes);         // 4 x chunked W8 bf16
    (void)in_sizes; (void)n_in; (void)out_size;

    wcvt_kernel<<<dim3(32, 4), 256, 0, stream>>>(wq, wk, wv, wp, Wbf);
    qkv_kernel<<<dim3(64, 4, 2), 256, 0, stream>>>(x, Wbf, bk, bv, KT, V);
    attn_kernel<<<dim3(256), 512, 0, stream>>>(KT, V, Wbf, bq, bp, x, (float*)d_out);
}

// Round 13
// 168.300 us; speedup vs baseline: 1.4476x; 1.1214x over previous
//
#include <hip/hip_runtime.h>
#include <hip/hip_bf16.h>

// NonLocalBlock B=4,C=256,H=W=64 (N=4096) — round 17.
//  Mechanism: MX-scaled fp8 MFMA (32x32x64 f8f6f4, fmt=fp8, scale=1.0) for
//  QK and PV: 4 MFMA/window each instead of 16, ~2x per-instr throughput,
//  half the accumulation-chain depth. Bytes moved are unchanged; correctness
//  relies on A/B symmetric k-map (permutation-invariant dot product) and the
//  shape-determined C/D layout (guide-verified dtype-independent).
//  Ps rows restrided 72->80B for b128-aligned consumer reads.
//  All else byte-identical to r16 (session best, 188.7us).
// ws = K8 | V8 | W8 = 8.5 MiB.

typedef __attribute__((ext_vector_type(4))) short s16x4;
typedef __attribute__((ext_vector_type(8))) short s16x8;
typedef __attribute__((ext_vector_type(16))) float f32x16;
typedef __attribute__((ext_vector_type(4))) int i32x4;
typedef __attribute__((ext_vector_type(8))) int i32x8;

#define MFMA32(a, b, c)   __builtin_amdgcn_mfma_f32_32x32x16_bf16((a), (b), (c), 0, 0, 0)
// scaled fp8, K=64; cbsz/blgp=0 -> e4m3; scale bytes 127 (E8M0) -> x1.0
#define MFMASC(a, b, c) __builtin_amdgcn_mfma_scale_f32_32x32x64_f8f6f4((a), (b), (c), 0, 0, 0, 127, 0, 127)

constexpr int Cc = 256;
constexpr int Nn = 4096;

__device__ inline short f2bf(float f) {
    unsigned int u = __builtin_bit_cast(unsigned int, f);
    u = (u + 0x7fffu + ((u >> 16) & 1u)) >> 16;   // RNE
    return (short)u;
}
__device__ inline unsigned char f2fp8(float f) {   // f32 -> OCP e4m3, RNE-sat
    return (unsigned char)(__builtin_amdgcn_cvt_pk_fp8_f32(f, f, 0, false) & 0xff);
}
__device__ inline i32x8 cat8(i32x4 lo, i32x4 hi) {
    i32x8 r;
    r[0] = lo[0]; r[1] = lo[1]; r[2] = lo[2]; r[3] = lo[3];
    r[4] = hi[0]; r[5] = hi[1]; r[6] = hi[2]; r[7] = hi[3];
    return r;
}

__device__ inline void gl_lds16(const void* g, void* l) {
    // async global->LDS, 16 B/lane; LDS dest = wave-uniform base + lane*16
    __builtin_amdgcn_global_load_lds((const unsigned int*)g, (unsigned int*)l, 16, 0, 0);
}

// 32x32 MFMA C/D (shape-determined, dtype-independent):
//   col=lane&31, row=(r&3)+8*(r>>2)+4*(lane>>5)
// A/B use symmetric per-lane k->byte maps -> any consistent k permutation ok.

// W8 chunked fragment: row in [0,256), kc = chunk index (8 k elems each)
#define WFRAG(Wm, row, kc) (*(const s16x8*)&(Wm)[(size_t)(kc)*2048 + (size_t)(row)*8])

// ---------------------------------------------------------------- wcvt
// fp32 [o][c] -> bf16 chunked W8[c>>3][o][c&7]  (weights stay bf16)
__global__ __launch_bounds__(256, 4) void wcvt_kernel(
    const float* __restrict__ wq, const float* __restrict__ wk,
    const float* __restrict__ wv, const float* __restrict__ wp,
    short* __restrict__ W)
{
    const int m = blockIdx.y;
    const float* src = (m == 0) ? wq : (m == 1) ? wk : (m == 2) ? wv : wp;
    const int idx = (blockIdx.x * 256 + threadIdx.x) * 8;
    const int o = idx >> 8, c0 = idx & 255;
    float4 a = *(const float4*)(src + idx);
    float4 b = *(const float4*)(src + idx + 4);
    s16x8 p = { f2bf(a.x), f2bf(a.y), f2bf(a.z), f2bf(a.w),
                f2bf(b.x), f2bf(b.y), f2bf(b.z), f2bf(b.w) };
    *(s16x8*)(W + m * 65536 + ((size_t)(c0 >> 3) * 256 + o) * 8) = p;
}

// ---------------------------------------------------------------- qkv (K,V only)
// grid (64 n-tiles, 4 b, 2 mat), 256 thr. GEMMs bf16; outputs quantized fp8.
// K8: row-major [n][c] fp8 (1B).  V8: chunked [j>>3][c][j&7] fp8.
__global__ __launch_bounds__(256, 4) void qkv_kernel(
    const float* __restrict__ x, const short* __restrict__ W,
    const float* __restrict__ bk, const float* __restrict__ bv,
    unsigned char* __restrict__ KT, unsigned char* __restrict__ V)
{
    const int nt = blockIdx.x, b = blockIdx.y, mat = blockIdx.z;  // 0=K 1=V
    const int n0 = nt * 64;
    const short* Wm = W + (mat + 1) * 65536;       // Wk slot 1, Wv slot 2
    const float* bias = (mat == 0) ? bk : bv;
    const int t = threadIdx.x, lane = t & 63, wid = t >> 6, h = lane >> 5, l31 = lane & 31;

    __shared__ alignas(16) short xT[64][264];      // x^T tile [n][c] bf16

    const float* xb = x + (size_t)b * Cc * Nn;
    #pragma unroll
    for (int r = 0; r < 16; ++r) {                 // transpose+cvt 64n x 256c
        int g = r * 256 + t;
        int n = g & 63, cg = g >> 6;
        float f0 = xb[(size_t)(4*cg + 0) * Nn + n0 + n];
        float f1 = xb[(size_t)(4*cg + 1) * Nn + n0 + n];
        float f2 = xb[(size_t)(4*cg + 2) * Nn + n0 + n];
        float f3 = xb[(size_t)(4*cg + 3) * Nn + n0 + n];
        s16x4 p = { f2bf(f0), f2bf(f1), f2bf(f2), f2bf(f3) };
        *(s16x4*)&xT[n][4*cg] = p;
    }
    __syncthreads();

    f32x16 acc[4];
    #pragma unroll
    for (int s = 0; s < 4; ++s)
        #pragma unroll
        for (int r = 0; r < 16; ++r) acc[s][r] = 0.f;

    if (mat == 0) {
        // K: D[n][o] = sum_c xT[n][c] w[o][c]
        const int mw = wid & 1, nwb = (wid >> 1) * 4;
        #pragma unroll 4
        for (int kk = 0; kk < 16; ++kk) {
            s16x8 a = *(const s16x8*)&xT[mw*32 + l31][kk*16 + h*8];
            #pragma unroll
            for (int s = 0; s < 4; ++s) {
                s16x8 bb = WFRAG(Wm, (nwb + s)*32 + l31, kk*2 + h);
                acc[s] = MFMA32(a, bb, acc[s]);
            }
        }
        unsigned char* dst = KT + (size_t)b * Nn * Cc;   // fp8 [n][c]
        #pragma unroll
        for (int s = 0; s < 4; ++s) {
            int o = (nwb + s)*32 + l31;
            float bia = bias[o];
            #pragma unroll
            for (int r = 0; r < 16; ++r) {
                int n = mw*32 + (r & 3) + 8*(r >> 2) + 4*h;
                dst[(size_t)(n0 + n) * Cc + o] = f2fp8(acc[s][r] + bia);
            }
        }
    } else {
        // V: D[o][n] = sum_c w[o][c] xT[n][c]
        #pragma unroll 4
        for (int kk = 0; kk < 16; ++kk) {
            s16x8 a0 = WFRAG(Wm, (wid*2 + 0)*32 + l31, kk*2 + h);
            s16x8 a1 = WFRAG(Wm, (wid*2 + 1)*32 + l31, kk*2 + h);
            s16x8 b0 = *(const s16x8*)&xT[ 0 + l31][kk*16 + h*8];
            s16x8 b1 = *(const s16x8*)&xT[32 + l31][kk*16 + h*8];
            acc[0] = MFMA32(a0, b0, acc[0]);
            acc[1] = MFMA32(a0, b1, acc[1]);
            acc[2] = MFMA32(a1, b0, acc[2]);
            acc[3] = MFMA32(a1, b1, acc[3]);
        }
        unsigned char* dst = V + (size_t)b * Cc * Nn;    // fp8 chunked V8
        #pragma unroll
        for (int sub = 0; sub < 4; ++sub) {
            int mc = sub >> 1, nc = sub & 1;
            int j = n0 + nc*32 + l31;
            #pragma unroll
            for (int r = 0; r < 16; ++r) {
                int o = (wid*2 + mc)*32 + (r & 3) + 8*(r >> 2) + 4*h;
                dst[(((size_t)(j >> 3) * 256 + o) << 3) + (j & 7)] = f2fp8(acc[sub][r] + bias[o]);
            }
        }
    }
}

// ---------------------------------------------------------------- attn (+Q, +proj fused; MX fp8 core)
// Structure = r16 exactly; QK/PV use K=64 scaled fp8 MFMA (4 each/window).
// LDS map: [0,32768) Ks | [32768,49152) Fq | [49152,59392) Ps (2x64x80B) |
// [65536,66048) lpart | [66048,66304) linv.  T/F epilogue overlays [0,65536).
__global__ __launch_bounds__(512, 2) void attn_kernel(
    const unsigned char* __restrict__ KTg, const unsigned char* __restrict__ Vg,
    const short* __restrict__ Wg, const float* __restrict__ bq,
    const float* __restrict__ bp, const float* __restrict__ xg,
    float* __restrict__ outg)
{
    const int bid = blockIdx.x;
    const int b  = (bid & 7) >> 1;              // batch per XCD pair
    const int qt = ((bid >> 3) << 1) | (bid & 1);
    const int i0 = qt * 64;

    const int t = threadIdx.x, lane = t & 63, wid = t >> 6, h = lane >> 5, l31 = lane & 31;

    __shared__ alignas(16) char LDS[66304];
    char* KsB = LDS;                            // [2][64][256] fp8 K staging
    unsigned char* FqB = (unsigned char*)(LDS + 32768);  // [64][256] fp8 Q
    char* PsB = LDS + 49152;                    // [2][64][80] fp8 P
    float* lpart = (float*)(LDS + 65536);       // [2][64]
    float* linv  = (float*)(LDS + 66048);       // [64]

    const unsigned char* Kb = KTg + (size_t)b * Nn * Cc;  // fp8 [j][c]
    const unsigned char* Vb = Vg  + (size_t)b * Cc * Nn;  // fp8 chunked V8
    const float* xb = xg + (size_t)b * Cc * Nn;

    const float SC = 0.09016844005f;            // C^-0.5 * log2(e)
    f32x16 oacc[4];

    // ---------------- prologue: Q[i0..i0+63][256] in-kernel (bf16 GEMM -> fp8 Fq)
    {
        short* xTp = (short*)LDS;                // 64 rows x 512 B bf16 (over Ks)
        #pragma unroll
        for (int r = 0; r < 8; ++r) {            // transpose+cvt 64n x 256c
            int g = r * 512 + t;
            int n = g & 63, cg = g >> 6;         // c = 4*cg
            float f0 = xb[(size_t)(4*cg + 0) * Nn + i0 + n];
            float f1 = xb[(size_t)(4*cg + 1) * Nn + i0 + n];
            float f2 = xb[(size_t)(4*cg + 2) * Nn + i0 + n];
            float f3 = xb[(size_t)(4*cg + 3) * Nn + i0 + n];
            s16x4 p = { f2bf(f0), f2bf(f1), f2bf(f2), f2bf(f3) };
            int bcol = (((cg >> 1) ^ (n & 15)) << 4) + (cg & 1) * 8;
            *(s16x4*)((char*)xTp + n * 512 + bcol) = p;
        }
        __syncthreads();

        const short* Wq = Wg;                    // mat 0 chunked bf16
        f32x16 qa[2];
        #pragma unroll
        for (int s = 0; s < 2; ++s)
            #pragma unroll
            for (int r = 0; r < 16; ++r) qa[s][r] = 0.f;
        #pragma unroll 4
        for (int kk = 0; kk < 16; ++kk) {
            int gsw = ((kk*2 + h) ^ (l31 & 15)) << 4;
            s16x8 a0 = *(const s16x8*)((char*)xTp + ( 0 + l31) * 512 + gsw);
            s16x8 a1 = *(const s16x8*)((char*)xTp + (32 + l31) * 512 + gsw);
            s16x8 bb = WFRAG(Wq, wid*32 + l31, kk*2 + h);
            qa[0] = MFMA32(a0, bb, qa[0]);
            qa[1] = MFMA32(a1, bb, qa[1]);
        }
        // D + bq -> Fq fp8 (separate region; 16B-granule XOR swizzle on o)
        const int o = wid*32 + l31;
        const float bo = bq[o];
        #pragma unroll
        for (int mw2 = 0; mw2 < 2; ++mw2)
            #pragma unroll
            for (int r = 0; r < 16; ++r) {
                int n = mw2*32 + (r & 3) + 8*(r >> 2) + 4*h;
                FqB[n*256 + (((o >> 4) ^ (n & 15)) << 4) + (o & 15)] = f2fp8(qa[mw2][r] + bo);
            }
    }
    __syncthreads();

    if (wid < 4) {
        // ---------------- producer: S^T = K Q^T (K=64 scaled fp8), exp, P fp8
        const int w4 = wid, mj = w4 >> 1, ni = w4 & 1;

        i32x8 qf[4];                             // 32B fp8 frags from Fq
        {
            const int qrow = ni*32 + l31, qsw = qrow & 15;
            #pragma unroll
            for (int q = 0; q < 4; ++q) {
                i32x4 lo = *(const i32x4*)(FqB + qrow*256 + (((q*4 + h*2 + 0) ^ qsw) << 4));
                i32x4 hi = *(const i32x4*)(FqB + qrow*256 + (((q*4 + h*2 + 1) ^ qsw) << 4));
                qf[q] = cat8(lo, hi);
            }
        }
        float lacc = 0.f;
        const int rl = mj*32 + l31;              // A-frag row (j)
        const int ip = ni*32 + l31;
        const int rsw = rl & 15;

        for (int tt = 0; tt < 66; ++tt) {
            if (tt < 64) {                       // stage K tile tt: 4 gl_lds/wave
                const int kb = tt & 1;
                #pragma unroll
                for (int it = 0; it < 4; ++it) {
                    int r = w4*16 + it*4 + (lane >> 4);
                    int g = (lane & 15) ^ (r & 15);
                    const unsigned char* gp = Kb + (size_t)(tt*64 + r) * Cc + g*16;
                    char* lp = KsB + kb*16384 + (w4*16 + it*4)*256;  // wave-uniform
                    gl_lds16(gp, lp);
                }
            }
            if (tt >= 1 && tt < 65) {
                const int jt = tt - 1, kb = jt & 1;
                const char* abase = KsB + kb*16384 + rl*256;
                f32x16 s;
                #pragma unroll
                for (int r = 0; r < 16; ++r) s[r] = 0.f;
                #pragma unroll
                for (int q = 0; q < 4; ++q) {
                    i32x4 lo = *(const i32x4*)(abase + (((q*4 + h*2 + 0) ^ rsw) << 4));
                    i32x4 hi = *(const i32x4*)(abase + (((q*4 + h*2 + 1) ^ rsw) << 4));
                    s = MFMASC(cat8(lo, hi), qf[q], s);
                }
                float ps[16], lsum = 0.f;
                #pragma unroll
                for (int r = 0; r < 16; ++r) {
                    float e = exp2f(s[r] * SC);
                    ps[r] = e; lsum += e;
                }
                lsum += __shfl_xor(lsum, 32);
                lacc += lsum;
                char* pw = PsB + kb*5120 + ip*80 + mj*32 + 4*h;
                #pragma unroll
                for (int g = 0; g < 4; ++g) {    // pack 4 fp8 via 2 cvt_pk
                    int w = __builtin_amdgcn_cvt_pk_fp8_f32(ps[4*g+0], ps[4*g+1], 0, false);
                    w = __builtin_amdgcn_cvt_pk_fp8_f32(ps[4*g+2], ps[4*g+3], w, true);
                    *(int*)(pw + g*8) = w;
                }
            }
            __syncthreads();                     // producer: full drain (Ks + Ps publish)
        }
        if (h == 0) lpart[mj*64 + ip] = lacc;
    } else {
        // ---------------- consumer: O^T[c][i] += V[c][j] P[i][j] (K=64 scaled fp8)
        const int w2 = wid - 4;
        #pragma unroll
        for (int s = 0; s < 4; ++s)
            #pragma unroll
            for (int r = 0; r < 16; ++r) oacc[s][r] = 0.f;

        i32x8 vA0, vA1, vB0, vB1;
        const unsigned char* vb0 = Vb + (size_t)(w2*64 +  0 + l31) * 8;
        const unsigned char* vb1 = Vb + (size_t)(w2*64 + 32 + l31) * 8;

        for (int tp = 0; tp < 33; ++tp) {
            const int t0 = tp*2, t1 = t0 + 1;
            // even step t0: issue tile t0-1 -> vA ; consume tile t0-2 from vB
            if (t0 >= 1 && t0 <= 64) {
                const size_t jc = (size_t)(t0 - 1) * 8;
                #pragma unroll
                for (int m = 0; m < 4; ++m) {
                    long v0 = *(const long*)(vb0 + (jc + h*4 + m) * 2048);
                    long v1 = *(const long*)(vb1 + (jc + h*4 + m) * 2048);
                    vA0[2*m] = (int)v0; vA0[2*m+1] = (int)((unsigned long)v0 >> 32);
                    vA1[2*m] = (int)v1; vA1[2*m+1] = (int)((unsigned long)v1 >> 32);
                }
            }
            if (t0 >= 2) {
                const int pb = (t0 - 2) & 1;
                const char* pr = PsB + pb*5120 + l31*80 + h*32;
                i32x8 p0 = cat8(*(const i32x4*)(pr),        *(const i32x4*)(pr + 16));
                i32x8 p1 = cat8(*(const i32x4*)(pr + 2560), *(const i32x4*)(pr + 2576));
                oacc[0] = MFMASC(vB0, p0, oacc[0]);
                oacc[1] = MFMASC(vB0, p1, oacc[1]);
                oacc[2] = MFMASC(vB1, p0, oacc[2]);
                oacc[3] = MFMASC(vB1, p1, oacc[3]);
            }
            asm volatile("s_barrier" ::: "memory");   // no drain: V stays in flight
            // odd step t1: issue tile t1-1 -> vB ; consume tile t1-2 from vA
            if (t1 <= 64) {
                const size_t jc = (size_t)(t1 - 1) * 8;
                #pragma unroll
                for (int m = 0; m < 4; ++m) {
                    long v0 = *(const long*)(vb0 + (jc + h*4 + m) * 2048);
                    long v1 = *(const long*)(vb1 + (jc + h*4 + m) * 2048);
                    vB0[2*m] = (int)v0; vB0[2*m+1] = (int)((unsigned long)v0 >> 32);
                    vB1[2*m] = (int)v1; vB1[2*m+1] = (int)((unsigned long)v1 >> 32);
                }
            }
            if (t1 >= 2) {
                const int pb = (t1 - 2) & 1;
                const char* pr = PsB + pb*5120 + l31*80 + h*32;
                i32x8 p0 = cat8(*(const i32x4*)(pr),        *(const i32x4*)(pr + 16));
                i32x8 p1 = cat8(*(const i32x4*)(pr + 2560), *(const i32x4*)(pr + 2576));
                oacc[0] = MFMASC(vA0, p0, oacc[0]);
                oacc[1] = MFMASC(vA0, p1, oacc[1]);
                oacc[2] = MFMASC(vA1, p0, oacc[2]);
                oacc[3] = MFMASC(vA1, p1, oacc[3]);
            }
            asm volatile("s_barrier" ::: "memory");
        }
    }

    // ---------------- epilogue A: normalize, LDS-transpose O -> T[n][c] (bf16)
    __syncthreads();
    if (t < 64) linv[t] = 1.0f / (lpart[t] + lpart[64 + t]);
    __syncthreads();
    short (*T)[264] = (short(*)[264])LDS;       // overlays Ks+Fq head (dead)
    if (wid >= 4) {
        const int w2 = wid - 4;
        #pragma unroll
        for (int sub = 0; sub < 4; ++sub) {
            int mc = sub >> 1, nc = sub & 1;
            int ip = nc*32 + l31;
            float rl2 = linv[ip];
            #pragma unroll
            for (int r = 0; r < 16; ++r) {
                int c = w2*64 + mc*32 + (r & 3) + 8*(r >> 2) + 4*h;
                T[ip][c] = f2bf(oacc[sub][r] * rl2);
            }
        }
    }
    __syncthreads();

    // ---------------- epilogue B: fused proj (bf16). D[n][o] = sum_c T[n][c] Wp[o][c]
    {
        const short* Wp = Wg + 3 * 65536;
        f32x16 acc2[2];
        #pragma unroll
        for (int s = 0; s < 2; ++s)
            #pragma unroll
            for (int r = 0; r < 16; ++r) acc2[s][r] = 0.f;

        #pragma unroll 4
        for (int kk = 0; kk < 16; ++kk) {
            s16x8 a0 = *(const s16x8*)&T[ 0 + l31][kk*16 + h*8];
            s16x8 a1 = *(const s16x8*)&T[32 + l31][kk*16 + h*8];
            s16x8 bb = WFRAG(Wp, wid*32 + l31, kk*2 + h);
            acc2[0] = MFMA32(a0, bb, acc2[0]);
            acc2[1] = MFMA32(a1, bb, acc2[1]);
        }
        __syncthreads();                         // all waves done reading T

        // bounce acc2 through XOR-swizzled fp32 tile F[n][o^(n&31)]
        float (*F)[256] = (float(*)[256])LDS;    // 64n x 256o fp32 = 64 KB
        {
            const int o = wid*32 + l31;
            #pragma unroll
            for (int nh = 0; nh < 2; ++nh) {
                #pragma unroll
                for (int r = 0; r < 16; ++r) {
                    int n = nh*32 + (r & 3) + 8*(r >> 2) + 4*h;
                    F[n][o ^ (n & 31)] = acc2[nh][r];
                }
            }
        }
        __syncthreads();

        // coalesced residual+store: lanes take consecutive n, fixed o
        float* ob = outg + (size_t)b * Cc * Nn;
        #pragma unroll 8
        for (int it = 0; it < 32; ++it) {
            int o = it*8 + wid;
            size_t idx = (size_t)o * Nn + i0 + lane;
            ob[idx] = xb[idx] + F[lane][o ^ (lane & 31)] + bp[o];
        }
    }
}

// ---------------------------------------------------------------- launch
extern "C" void kernel_launch(void* const* d_in, const int* in_sizes, int n_in,
                              void* d_out, int out_size, void* d_ws, size_t ws_size,
                              hipStream_t stream)
{
    const float* x  = (const float*)d_in[0];
    const float* wq = (const float*)d_in[1];
    const float* bq = (const float*)d_in[2];
    const float* wk = (const float*)d_in[3];
    const float* bk = (const float*)d_in[4];
    const float* wv = (const float*)d_in[5];
    const float* bv = (const float*)d_in[6];
    const float* wp = (const float*)d_in[7];
    const float* bp = (const float*)d_in[8];

    const size_t kvbytes = (size_t)4 * Nn * Cc;            // 4 MiB per fp8 buffer
    const size_t wel     = (size_t)4 * 65536;              // W8 shorts
    const size_t need    = 2 * kvbytes + wel * sizeof(short);   // ~8.5 MiB
    if (ws_size < need) return;
    unsigned char* KT = (unsigned char*)d_ws;   // [b][n][c] fp8
    unsigned char* V  = KT + kvbytes;           // [b] chunked V8 fp8
    short* Wbf = (short*)(V + kvbytes);         // 4 x chunked W8 bf16
    (void)in_sizes; (void)n_in; (void)out_size;

    wcvt_kernel<<<dim3(32, 4), 256, 0, stream>>>(wq, wk, wv, wp, Wbf);
    qkv_kernel<<<dim3(64, 4, 2), 256, 0, stream>>>(x, Wbf, bk, bv, KT, V);
    attn_kernel<<<dim3(256), 512, 0, stream>>>(KT, V, Wbf, bq, bp, x, (float*)d_out);
}

// Round 14
// 152.425 us; speedup vs baseline: 1.5984x; 1.1042x over previous
//
#include <hip/hip_runtime.h>
#include <hip/hip_bf16.h>

// NonLocalBlock B=4,C=256,H=W=64 (N=4096) — round 18.
//  (a) attn producer VALU diet: per-window shfl_xor(lsum) deferred to ONE
//      post-loop shfl (h-halves accumulate privately); softmax scale folded
//      into MX scale (Q quantized as Q*log2e, QK scale byte 123 = 2^-4;
//      0.0625*1.4427 = C^-0.5*log2e exactly) -> 16 v_mul + 1 shfl deleted
//      per producer window.
//  (b) qkv MX-fp8 GEMMs: x quantized fp8 in transpose (16KB LDS, 16B-granule
//      XOR swizzle, same pattern as attn Fq); wcvt emits extra fp8 chunked
//      Wk/Wv; K/V GEMMs = 16 MFMASC(K=64)/wave instead of 64 bf16 MFMA.
//  attn structure/layout otherwise identical to r17 (session best, 168.3us).
// ws = K8 | V8 | W8(bf16) | W8f(fp8 K,V) = 8.6 MiB.

typedef __attribute__((ext_vector_type(4))) short s16x4;
typedef __attribute__((ext_vector_type(8))) short s16x8;
typedef __attribute__((ext_vector_type(16))) float f32x16;
typedef __attribute__((ext_vector_type(4))) int i32x4;
typedef __attribute__((ext_vector_type(8))) int i32x8;

#define MFMA32(a, b, c)   __builtin_amdgcn_mfma_f32_32x32x16_bf16((a), (b), (c), 0, 0, 0)
// scaled fp8 K=64. MFMASC: scales 1.0/1.0.  MFMASC_Q: one scale 2^-4 (123)
// -> product scaled by 2^-4; with Q pre-scaled by log2e this equals SC.
#define MFMASC(a, b, c)   __builtin_amdgcn_mfma_scale_f32_32x32x64_f8f6f4((a), (b), (c), 0, 0, 0, 127, 0, 127)
#define MFMASC_Q(a, b, c) __builtin_amdgcn_mfma_scale_f32_32x32x64_f8f6f4((a), (b), (c), 0, 0, 0, 123, 0, 127)

constexpr int Cc = 256;
constexpr int Nn = 4096;

__device__ inline short f2bf(float f) {
    unsigned int u = __builtin_bit_cast(unsigned int, f);
    u = (u + 0x7fffu + ((u >> 16) & 1u)) >> 16;   // RNE
    return (short)u;
}
__device__ inline unsigned char f2fp8(float f) {   // f32 -> OCP e4m3, RNE-sat
    return (unsigned char)(__builtin_amdgcn_cvt_pk_fp8_f32(f, f, 0, false) & 0xff);
}
__device__ inline i32x8 cat8(i32x4 lo, i32x4 hi) {
    i32x8 r;
    r[0] = lo[0]; r[1] = lo[1]; r[2] = lo[2]; r[3] = lo[3];
    r[4] = hi[0]; r[5] = hi[1]; r[6] = hi[2]; r[7] = hi[3];
    return r;
}

__device__ inline void gl_lds16(const void* g, void* l) {
    // async global->LDS, 16 B/lane; LDS dest = wave-uniform base + lane*16
    __builtin_amdgcn_global_load_lds((const unsigned int*)g, (unsigned int*)l, 16, 0, 0);
}

// 32x32 MFMA C/D (shape-determined, dtype-independent):
//   col=lane&31, row=(r&3)+8*(r>>2)+4*(lane>>5)
// A/B frags feed identical per-lane byte->c maps -> dot product exact.

// W8 bf16 chunked fragment: row in [0,256), kc = 8-elem chunk index
#define WFRAG(Wm, row, kc) (*(const s16x8*)&(Wm)[(size_t)(kc)*2048 + (size_t)(row)*8])
// W8f fp8 chunked: [c>>4][o][c&15]; 16B granule g of row o at (g*256+o)*16
#define WF8(Wf, row, g) (*(const i32x4*)&(Wf)[((size_t)(g)*256 + (row)) * 16])

// ---------------------------------------------------------------- wcvt
// fp32 [o][c] -> bf16 chunked W8 (all 4 mats) + fp8 chunked W8f (Wk, Wv)
__global__ __launch_bounds__(256, 4) void wcvt_kernel(
    const float* __restrict__ wq, const float* __restrict__ wk,
    const float* __restrict__ wv, const float* __restrict__ wp,
    short* __restrict__ W, unsigned char* __restrict__ W8f)
{
    const int m = blockIdx.y;
    const float* src = (m == 0) ? wq : (m == 1) ? wk : (m == 2) ? wv : wp;
    const int idx = (blockIdx.x * 256 + threadIdx.x) * 8;
    const int o = idx >> 8, c0 = idx & 255;
    float4 a = *(const float4*)(src + idx);
    float4 b = *(const float4*)(src + idx + 4);
    s16x8 p = { f2bf(a.x), f2bf(a.y), f2bf(a.z), f2bf(a.w),
                f2bf(b.x), f2bf(b.y), f2bf(b.z), f2bf(b.w) };
    *(s16x8*)(W + m * 65536 + ((size_t)(c0 >> 3) * 256 + o) * 8) = p;
    if (m == 1 || m == 2) {                       // fp8 copy for qkv GEMMs
        unsigned char* Wf = W8f + (m - 1) * 65536;
        int w0 = __builtin_amdgcn_cvt_pk_fp8_f32(a.x, a.y, 0, false);
        w0 = __builtin_amdgcn_cvt_pk_fp8_f32(a.z, a.w, w0, true);
        int w1 = __builtin_amdgcn_cvt_pk_fp8_f32(b.x, b.y, 0, false);
        w1 = __builtin_amdgcn_cvt_pk_fp8_f32(b.z, b.w, w1, true);
        unsigned char* dst = Wf + (((size_t)(c0 >> 4) * 256 + o) * 16) + (c0 & 15);
        *(int*)(dst) = w0; *(int*)(dst + 4) = w1;
    }
}

// ---------------------------------------------------------------- qkv (K,V only; MX-fp8 GEMMs)
// grid (64 n-tiles, 4 b, 2 mat), 256 thr. xT quantized fp8 in LDS (16KB,
// 16B-granule XOR swizzle g^(n&15)); 16 MFMASC(K=64)/wave.
__global__ __launch_bounds__(256, 4) void qkv_kernel(
    const float* __restrict__ x, const unsigned char* __restrict__ W8f,
    const float* __restrict__ bk, const float* __restrict__ bv,
    unsigned char* __restrict__ KT, unsigned char* __restrict__ V)
{
    const int nt = blockIdx.x, b = blockIdx.y, mat = blockIdx.z;  // 0=K 1=V
    const int n0 = nt * 64;
    const unsigned char* Wf = W8f + mat * 65536;
    const float* bias = (mat == 0) ? bk : bv;
    const int t = threadIdx.x, lane = t & 63, wid = t >> 6, h = lane >> 5, l31 = lane & 31;

    __shared__ alignas(16) unsigned char xT[64 * 256];   // fp8, swizzled

    const float* xb = x + (size_t)b * Cc * Nn;
    #pragma unroll
    for (int r = 0; r < 16; ++r) {                 // transpose+quant 64n x 256c
        int g = r * 256 + t;
        int n = g & 63, cg = g >> 6;               // c = 4*cg
        float f0 = xb[(size_t)(4*cg + 0) * Nn + n0 + n];
        float f1 = xb[(size_t)(4*cg + 1) * Nn + n0 + n];
        float f2 = xb[(size_t)(4*cg + 2) * Nn + n0 + n];
        float f3 = xb[(size_t)(4*cg + 3) * Nn + n0 + n];
        int w = __builtin_amdgcn_cvt_pk_fp8_f32(f0, f1, 0, false);
        w = __builtin_amdgcn_cvt_pk_fp8_f32(f2, f3, w, true);
        *(int*)(xT + n*256 + ((((cg >> 2) ^ (n & 15)) << 4) | (4*cg & 15))) = w;
    }
    __syncthreads();

    f32x16 acc[4];
    #pragma unroll
    for (int s = 0; s < 4; ++s)
        #pragma unroll
        for (int r = 0; r < 16; ++r) acc[s][r] = 0.f;

    if (mat == 0) {
        // K: D[n][o] = sum_c xT[n][c] Wk[o][c]  (A = xT fp8, B = Wf fp8)
        const int mw = wid & 1, nwb = (wid >> 1) * 4;
        const int arow = mw*32 + l31, asw = arow & 15;
        #pragma unroll
        for (int q = 0; q < 4; ++q) {
            i32x4 alo = *(const i32x4*)(xT + arow*256 + (((q*4 + h*2 + 0) ^ asw) << 4));
            i32x4 ahi = *(const i32x4*)(xT + arow*256 + (((q*4 + h*2 + 1) ^ asw) << 4));
            i32x8 a = cat8(alo, ahi);
            #pragma unroll
            for (int s = 0; s < 4; ++s) {
                int o = (nwb + s)*32 + l31;
                i32x8 bb = cat8(WF8(Wf, o, q*4 + h*2 + 0), WF8(Wf, o, q*4 + h*2 + 1));
                acc[s] = MFMASC(a, bb, acc[s]);
            }
        }
        unsigned char* dst = KT + (size_t)b * Nn * Cc;   // fp8 [n][c]
        #pragma unroll
        for (int s = 0; s < 4; ++s) {
            int o = (nwb + s)*32 + l31;
            float bia = bias[o];
            #pragma unroll
            for (int r = 0; r < 16; ++r) {
                int n = mw*32 + (r & 3) + 8*(r >> 2) + 4*h;
                dst[(size_t)(n0 + n) * Cc + o] = f2fp8(acc[s][r] + bia);
            }
        }
    } else {
        // V: D[o][n] = sum_c Wv[o][c] xT[n][c]  (A = Wf fp8, B = xT fp8)
        const int b0r = 0 + l31, b1r = 32 + l31;
        #pragma unroll
        for (int q = 0; q < 4; ++q) {
            int g0 = q*4 + h*2 + 0, g1 = q*4 + h*2 + 1;
            i32x8 a0 = cat8(WF8(Wf, (wid*2 + 0)*32 + l31, g0), WF8(Wf, (wid*2 + 0)*32 + l31, g1));
            i32x8 a1 = cat8(WF8(Wf, (wid*2 + 1)*32 + l31, g0), WF8(Wf, (wid*2 + 1)*32 + l31, g1));
            i32x8 b0 = cat8(*(const i32x4*)(xT + b0r*256 + ((g0 ^ (b0r & 15)) << 4)),
                            *(const i32x4*)(xT + b0r*256 + ((g1 ^ (b0r & 15)) << 4)));
            i32x8 b1 = cat8(*(const i32x4*)(xT + b1r*256 + ((g0 ^ (b1r & 15)) << 4)),
                            *(const i32x4*)(xT + b1r*256 + ((g1 ^ (b1r & 15)) << 4)));
            acc[0] = MFMASC(a0, b0, acc[0]);
            acc[1] = MFMASC(a0, b1, acc[1]);
            acc[2] = MFMASC(a1, b0, acc[2]);
            acc[3] = MFMASC(a1, b1, acc[3]);
        }
        unsigned char* dst = V + (size_t)b * Cc * Nn;    // fp8 chunked V8
        #pragma unroll
        for (int sub = 0; sub < 4; ++sub) {
            int mc = sub >> 1, nc = sub & 1;
            int j = n0 + nc*32 + l31;
            #pragma unroll
            for (int r = 0; r < 16; ++r) {
                int o = (wid*2 + mc)*32 + (r & 3) + 8*(r >> 2) + 4*h;
                dst[(((size_t)(j >> 3) * 256 + o) << 3) + (j & 7)] = f2fp8(acc[sub][r] + bias[o]);
            }
        }
    }
}

// ---------------------------------------------------------------- attn (+Q, +proj fused; MX fp8 core)
// Structure = r17. Deltas: Q stored as Q*log2e; QK uses MFMASC_Q (scale 2^-4
// -> S pre-scaled by SC, exp2 directly, no per-window mul); lsum shfl
// deferred to one post-loop shfl.
__global__ __launch_bounds__(512, 2) void attn_kernel(
    const unsigned char* __restrict__ KTg, const unsigned char* __restrict__ Vg,
    const short* __restrict__ Wg, const float* __restrict__ bq,
    const float* __restrict__ bp, const float* __restrict__ xg,
    float* __restrict__ outg)
{
    const int bid = blockIdx.x;
    const int b  = (bid & 7) >> 1;              // batch per XCD pair
    const int qt = ((bid >> 3) << 1) | (bid & 1);
    const int i0 = qt * 64;

    const int t = threadIdx.x, lane = t & 63, wid = t >> 6, h = lane >> 5, l31 = lane & 31;

    __shared__ alignas(16) char LDS[66304];
    char* KsB = LDS;                            // [2][64][256] fp8 K staging
    unsigned char* FqB = (unsigned char*)(LDS + 32768);  // [64][256] fp8 Q*log2e
    char* PsB = LDS + 49152;                    // [2][64][80] fp8 P
    float* lpart = (float*)(LDS + 65536);       // [2][64]
    float* linv  = (float*)(LDS + 66048);       // [64]

    const unsigned char* Kb = KTg + (size_t)b * Nn * Cc;  // fp8 [j][c]
    const unsigned char* Vb = Vg  + (size_t)b * Cc * Nn;  // fp8 chunked V8
    const float* xb = xg + (size_t)b * Cc * Nn;

    const float L2E = 1.4426950408889634f;      // log2(e); with 2^-4 MX scale
    f32x16 oacc[4];                             //   product scale = C^-0.5*log2e

    // ---------------- prologue: Q[i0..i0+63][256] in-kernel (bf16 GEMM -> fp8 Fq)
    {
        short* xTp = (short*)LDS;                // 64 rows x 512 B bf16 (over Ks)
        #pragma unroll
        for (int r = 0; r < 8; ++r) {            // transpose+cvt 64n x 256c
            int g = r * 512 + t;
            int n = g & 63, cg = g >> 6;         // c = 4*cg
            float f0 = xb[(size_t)(4*cg + 0) * Nn + i0 + n];
            float f1 = xb[(size_t)(4*cg + 1) * Nn + i0 + n];
            float f2 = xb[(size_t)(4*cg + 2) * Nn + i0 + n];
            float f3 = xb[(size_t)(4*cg + 3) * Nn + i0 + n];
            s16x4 p = { f2bf(f0), f2bf(f1), f2bf(f2), f2bf(f3) };
            int bcol = (((cg >> 1) ^ (n & 15)) << 4) + (cg & 1) * 8;
            *(s16x4*)((char*)xTp + n * 512 + bcol) = p;
        }
        __syncthreads();

        const short* Wq = Wg;                    // mat 0 chunked bf16
        f32x16 qa[2];
        #pragma unroll
        for (int s = 0; s < 2; ++s)
            #pragma unroll
            for (int r = 0; r < 16; ++r) qa[s][r] = 0.f;
        #pragma unroll 4
        for (int kk = 0; kk < 16; ++kk) {
            int gsw = ((kk*2 + h) ^ (l31 & 15)) << 4;
            s16x8 a0 = *(const s16x8*)((char*)xTp + ( 0 + l31) * 512 + gsw);
            s16x8 a1 = *(const s16x8*)((char*)xTp + (32 + l31) * 512 + gsw);
            s16x8 bb = WFRAG(Wq, wid*32 + l31, kk*2 + h);
            qa[0] = MFMA32(a0, bb, qa[0]);
            qa[1] = MFMA32(a1, bb, qa[1]);
        }
        // (Q + bq)*log2e -> Fq fp8 (16B-granule XOR swizzle on o)
        const int o = wid*32 + l31;
        const float bo = bq[o];
        #pragma unroll
        for (int mw2 = 0; mw2 < 2; ++mw2)
            #pragma unroll
            for (int r = 0; r < 16; ++r) {
                int n = mw2*32 + (r & 3) + 8*(r >> 2) + 4*h;
                FqB[n*256 + (((o >> 4) ^ (n & 15)) << 4) + (o & 15)] =
                    f2fp8((qa[mw2][r] + bo) * L2E);
            }
    }
    __syncthreads();

    if (wid < 4) {
        // ---------------- producer: S = K Q^T * SC (MX-scaled), exp2, P fp8
        const int w4 = wid, mj = w4 >> 1, ni = w4 & 1;

        i32x8 qf[4];                             // 32B fp8 frags from Fq
        {
            const int qrow = ni*32 + l31, qsw = qrow & 15;
            #pragma unroll
            for (int q = 0; q < 4; ++q) {
                i32x4 lo = *(const i32x4*)(FqB + qrow*256 + (((q*4 + h*2 + 0) ^ qsw) << 4));
                i32x4 hi = *(const i32x4*)(FqB + qrow*256 + (((q*4 + h*2 + 1) ^ qsw) << 4));
                qf[q] = cat8(lo, hi);
            }
        }
        float lacc = 0.f;                        // h-private; combined post-loop
        const int rl = mj*32 + l31;              // A-frag row (j)
        const int ip = ni*32 + l31;
        const int rsw = rl & 15;

        for (int tt = 0; tt < 66; ++tt) {
            if (tt < 64) {                       // stage K tile tt: 4 gl_lds/wave
                const int kb = tt & 1;
                #pragma unroll
                for (int it = 0; it < 4; ++it) {
                    int r = w4*16 + it*4 + (lane >> 4);
                    int g = (lane & 15) ^ (r & 15);
                    const unsigned char* gp = Kb + (size_t)(tt*64 + r) * Cc + g*16;
                    char* lp = KsB + kb*16384 + (w4*16 + it*4)*256;  // wave-uniform
                    gl_lds16(gp, lp);
                }
            }
            if (tt >= 1 && tt < 65) {
                const int jt = tt - 1, kb = jt & 1;
                const char* abase = KsB + kb*16384 + rl*256;
                f32x16 s;
                #pragma unroll
                for (int r = 0; r < 16; ++r) s[r] = 0.f;
                #pragma unroll
                for (int q = 0; q < 4; ++q) {
                    i32x4 lo = *(const i32x4*)(abase + (((q*4 + h*2 + 0) ^ rsw) << 4));
                    i32x4 hi = *(const i32x4*)(abase + (((q*4 + h*2 + 1) ^ rsw) << 4));
                    s = MFMASC_Q(cat8(lo, hi), qf[q], s);
                }
                float ps[16], lsum = 0.f;
                #pragma unroll
                for (int r = 0; r < 16; ++r) {
                    float e = exp2f(s[r]);       // scale already folded in
                    ps[r] = e; lsum += e;
                }
                lacc += lsum;                    // no per-window shfl
                char* pw = PsB + kb*5120 + ip*80 + mj*32 + 4*h;
                #pragma unroll
                for (int g = 0; g < 4; ++g) {    // pack 4 fp8 via 2 cvt_pk
                    int w = __builtin_amdgcn_cvt_pk_fp8_f32(ps[4*g+0], ps[4*g+1], 0, false);
                    w = __builtin_amdgcn_cvt_pk_fp8_f32(ps[4*g+2], ps[4*g+3], w, true);
                    *(int*)(pw + g*8) = w;
                }
            }
            __syncthreads();                     // producer: full drain (Ks + Ps publish)
        }
        lacc += __shfl_xor(lacc, 32);            // combine h-halves once
        if (h == 0) lpart[mj*64 + ip] = lacc;
    } else {
        // ---------------- consumer: O^T[c][i] += V[c][j] P[i][j] (K=64 scaled fp8)
        const int w2 = wid - 4;
        #pragma unroll
        for (int s = 0; s < 4; ++s)
            #pragma unroll
            for (int r = 0; r < 16; ++r) oacc[s][r] = 0.f;

        i32x8 vA0, vA1, vB0, vB1;
        const unsigned char* vb0 = Vb + (size_t)(w2*64 +  0 + l31) * 8;
        const unsigned char* vb1 = Vb + (size_t)(w2*64 + 32 + l31) * 8;

        for (int tp = 0; tp < 33; ++tp) {
            const int t0 = tp*2, t1 = t0 + 1;
            // even step t0: issue tile t0-1 -> vA ; consume tile t0-2 from vB
            if (t0 >= 1 && t0 <= 64) {
                const size_t jc = (size_t)(t0 - 1) * 8;
                #pragma unroll
                for (int m = 0; m < 4; ++m) {
                    long v0 = *(const long*)(vb0 + (jc + h*4 + m) * 2048);
                    long v1 = *(const long*)(vb1 + (jc + h*4 + m) * 2048);
                    vA0[2*m] = (int)v0; vA0[2*m+1] = (int)((unsigned long)v0 >> 32);
                    vA1[2*m] = (int)v1; vA1[2*m+1] = (int)((unsigned long)v1 >> 32);
                }
            }
            if (t0 >= 2) {
                const int pb = (t0 - 2) & 1;
                const char* pr = PsB + pb*5120 + l31*80 + h*32;
                i32x8 p0 = cat8(*(const i32x4*)(pr),        *(const i32x4*)(pr + 16));
                i32x8 p1 = cat8(*(const i32x4*)(pr + 2560), *(const i32x4*)(pr + 2576));
                oacc[0] = MFMASC(vB0, p0, oacc[0]);
                oacc[1] = MFMASC(vB0, p1, oacc[1]);
                oacc[2] = MFMASC(vB1, p0, oacc[2]);
                oacc[3] = MFMASC(vB1, p1, oacc[3]);
            }
            asm volatile("s_barrier" ::: "memory");   // no drain: V stays in flight
            // odd step t1: issue tile t1-1 -> vB ; consume tile t1-2 from vA
            if (t1 <= 64) {
                const size_t jc = (size_t)(t1 - 1) * 8;
                #pragma unroll
                for (int m = 0; m < 4; ++m) {
                    long v0 = *(const long*)(vb0 + (jc + h*4 + m) * 2048);
                    long v1 = *(const long*)(vb1 + (jc + h*4 + m) * 2048);
                    vB0[2*m] = (int)v0; vB0[2*m+1] = (int)((unsigned long)v0 >> 32);
                    vB1[2*m] = (int)v1; vB1[2*m+1] = (int)((unsigned long)v1 >> 32);
                }
            }
            if (t1 >= 2) {
                const int pb = (t1 - 2) & 1;
                const char* pr = PsB + pb*5120 + l31*80 + h*32;
                i32x8 p0 = cat8(*(const i32x4*)(pr),        *(const i32x4*)(pr + 16));
                i32x8 p1 = cat8(*(const i32x4*)(pr + 2560), *(const i32x4*)(pr + 2576));
                oacc[0] = MFMASC(vA0, p0, oacc[0]);
                oacc[1] = MFMASC(vA0, p1, oacc[1]);
                oacc[2] = MFMASC(vA1, p0, oacc[2]);
                oacc[3] = MFMASC(vA1, p1, oacc[3]);
            }
            asm volatile("s_barrier" ::: "memory");
        }
    }

    // ---------------- epilogue A: normalize, LDS-transpose O -> T[n][c] (bf16)
    __syncthreads();
    if (t < 64) linv[t] = 1.0f / (lpart[t] + lpart[64 + t]);
    __syncthreads();
    short (*T)[264] = (short(*)[264])LDS;       // overlays Ks+Fq head (dead)
    if (wid >= 4) {
        const int w2 = wid - 4;
        #pragma unroll
        for (int sub = 0; sub < 4; ++sub) {
            int mc = sub >> 1, nc = sub & 1;
            int ip = nc*32 + l31;
            float rl2 = linv[ip];
            #pragma unroll
            for (int r = 0; r < 16; ++r) {
                int c = w2*64 + mc*32 + (r & 3) + 8*(r >> 2) + 4*h;
                T[ip][c] = f2bf(oacc[sub][r] * rl2);
            }
        }
    }
    __syncthreads();

    // ---------------- epilogue B: fused proj (bf16). D[n][o] = sum_c T[n][c] Wp[o][c]
    {
        const short* Wp = Wg + 3 * 65536;
        f32x16 acc2[2];
        #pragma unroll
        for (int s = 0; s < 2; ++s)
            #pragma unroll
            for (int r = 0; r < 16; ++r) acc2[s][r] = 0.f;

        #pragma unroll 4
        for (int kk = 0; kk < 16; ++kk) {
            s16x8 a0 = *(const s16x8*)&T[ 0 + l31][kk*16 + h*8];
            s16x8 a1 = *(const s16x8*)&T[32 + l31][kk*16 + h*8];
            s16x8 bb = WFRAG(Wp, wid*32 + l31, kk*2 + h);
            acc2[0] = MFMA32(a0, bb, acc2[0]);
            acc2[1] = MFMA32(a1, bb, acc2[1]);
        }
        __syncthreads();                         // all waves done reading T

        // bounce acc2 through XOR-swizzled fp32 tile F[n][o^(n&31)]
        float (*F)[256] = (float(*)[256])LDS;    // 64n x 256o fp32 = 64 KB
        {
            const int o = wid*32 + l31;
            #pragma unroll
            for (int nh = 0; nh < 2; ++nh) {
                #pragma unroll
                for (int r = 0; r < 16; ++r) {
                    int n = nh*32 + (r & 3) + 8*(r >> 2) + 4*h;
                    F[n][o ^ (n & 31)] = acc2[nh][r];
                }
            }
        }
        __syncthreads();

        // coalesced residual+store: lanes take consecutive n, fixed o
        float* ob = outg + (size_t)b * Cc * Nn;
        #pragma unroll 8
        for (int it = 0; it < 32; ++it) {
            int o = it*8 + wid;
            size_t idx = (size_t)o * Nn + i0 + lane;
            ob[idx] = xb[idx] + F[lane][o ^ (lane & 31)] + bp[o];
        }
    }
}

// ---------------------------------------------------------------- launch
extern "C" void kernel_launch(void* const* d_in, const int* in_sizes, int n_in,
                              void* d_out, int out_size, void* d_ws, size_t ws_size,
                              hipStream_t stream)
{
    const float* x  = (const float*)d_in[0];
    const float* wq = (const float*)d_in[1];
    const float* bq = (const float*)d_in[2];
    const float* wk = (const float*)d_in[3];
    const float* bk = (const float*)d_in[4];
    const float* wv = (const float*)d_in[5];
    const float* bv = (const float*)d_in[6];
    const float* wp = (const float*)d_in[7];
    const float* bp = (const float*)d_in[8];

    const size_t kvbytes = (size_t)4 * Nn * Cc;            // 4 MiB per fp8 buffer
    const size_t wel     = (size_t)4 * 65536;              // W8 bf16 shorts
    const size_t wfb     = (size_t)2 * 65536;              // W8f fp8 bytes
    const size_t need    = 2 * kvbytes + wel * sizeof(short) + wfb;   // ~8.6 MiB
    if (ws_size < need) return;
    unsigned char* KT = (unsigned char*)d_ws;   // [b][n][c] fp8
    unsigned char* V  = KT + kvbytes;           // [b] chunked V8 fp8
    short* Wbf = (short*)(V + kvbytes);         // 4 x chunked W8 bf16
    unsigned char* W8f = (unsigned char*)(Wbf + wel);  // 2 x chunked fp8 (Wk,Wv)
    (void)in_sizes; (void)n_in; (void)out_size;

    wcvt_kernel<<<dim3(32, 4), 256, 0, stream>>>(wq, wk, wv, wp, Wbf, W8f);
    qkv_kernel<<<dim3(64, 4, 2), 256, 0, stream>>>(x, W8f, bk, bv, KT, V);
    attn_kernel<<<dim3(256), 512, 0, stream>>>(KT, V, Wbf, bq, bp, x, (float*)d_out);
}